// Round 3
// baseline (317.435 us; speedup 1.0000x reference)
//
#include <hip/hip_runtime.h>
#include <math.h>

#define WS_ 8
#define NH_ 8
#define C_ 256
#define B_ 8
#define M_ 32768            // B_*L_
#define SH_ 4               // WS_/2
#define LN_EPS 1e-5f
#define SL_ 8388608         // elements per [M,C] slot

typedef __attribute__((ext_vector_type(8))) short bf16x8;
typedef __attribute__((ext_vector_type(4))) float f32x4;

__device__ inline float b2f(unsigned short u) {
    union { unsigned int i; float f; } c; c.i = ((unsigned int)u) << 16; return c.f;
}
__device__ inline unsigned short f2b(float f) {
    union { unsigned int i; float f; } c; c.f = f;
    unsigned int u = c.i;
    return (unsigned short)((u + 0x7FFFu + ((u >> 16) & 1u)) >> 16);
}
__device__ inline float gelu_f(float x) {
    // tanh-form GELU: x * sigmoid(1.59576912*(x + 0.044715 x^3)); |err| < ~1e-3
    float t = 1.59576912160573f * (x + 0.044715f * x * x * x);
    return x / (1.f + __expf(-t));
}

// ---------- weight prep + adaln fused: bf16 [N][K] transposes, qkv bias,
// ---------- bias_full, and ss = t_embed @ w + b for both adaln layers -------
__global__ void prep_k(const float* __restrict__ qw, const float* __restrict__ kw,
                       const float* __restrict__ vw, const float* __restrict__ ow,
                       const float* __restrict__ f1w, const float* __restrict__ f2w,
                       const float* __restrict__ qb, const float* __restrict__ kb,
                       const float* __restrict__ vb, const float* __restrict__ bt,
                       const float* __restrict__ te,
                       const float* __restrict__ a1w, const float* __restrict__ a1b,
                       const float* __restrict__ a2w, const float* __restrict__ a2b,
                       unsigned short* __restrict__ qkvT, unsigned short* __restrict__ oT,
                       unsigned short* __restrict__ f1T, unsigned short* __restrict__ f2T,
                       float* __restrict__ qkvB, float* __restrict__ bias_full,
                       float* __restrict__ ss1, float* __restrict__ ss2) {
    int t = blockIdx.x * 256 + threadIdx.x;
    if (t < 196608) {                       // qkvT [768][256]
        int n = t >> 8, k = t & 255;
        const float* w = n < 256 ? qw : (n < 512 ? kw : vw);
        qkvT[t] = f2b(w[k * 256 + (n & 255)]);
    } else if (t < 262144) {                // oT [256][256]
        int i = t - 196608; int n = i >> 8, k = i & 255;
        oT[i] = f2b(ow[k * 256 + n]);
    } else if (t < 524288) {                // f1T [1024][256]
        int i = t - 262144; int n = i >> 8, k = i & 255;
        f1T[i] = f2b(f1w[k * 1024 + n]);
    } else if (t < 786432) {                // f2T [256][1024]
        int i = t - 524288; int n = i >> 10, k = i & 1023;
        f2T[i] = f2b(f2w[k * 256 + n]);
    } else if (t < 787200) {                // qkv bias [768]
        int i = t - 786432;
        qkvB[i] = i < 256 ? qb[i] : (i < 512 ? kb[i - 256] : vb[i - 512]);
    } else if (t < 819968) {                // bias_full [8][64][64]
        int i = t - 787200;
        int head = i >> 12, qk = i & 4095;
        int q = qk >> 6, k = qk & 63;
        int qh = q >> 3, qw2 = q & 7, kh = k >> 3, kw2 = k & 7;
        bias_full[i] = bt[((qh - kh + 7) * 15 + (qw2 - kw2 + 7)) * 8 + head];
    } else if (t < 828160) {                // adaln: 2 x [8][512]
        int i = t - 819968;
        int which = i >> 12;
        int rem = i & 4095;
        int b = rem >> 9, col = rem & 511;
        const float* w = which ? a2w : a1w;
        const float* bb = which ? a2b : a1b;
        const float* tr = te + b * C_;
        float acc = bb[col];
        for (int k = 0; k < C_; ++k) acc += tr[k] * w[k * 512 + col];
        (which ? ss2 : ss1)[b * 512 + col] = acc;
    }
}

// ------ LN + modulate + shift + window partition: one wave per token ---------
__global__ __launch_bounds__(256) void ln_win_k(const float* __restrict__ x,
                                                const float* __restrict__ ss,
                                                unsigned short* __restrict__ xw) {
    int t = blockIdx.x * 4 + (threadIdx.x >> 6);     // token 0..32767
    int lane = threadIdx.x & 63;
    int b = t >> 12, rem = t & 4095;
    int hg = rem >> 6, wg = rem & 63;
    int hs = (hg + SH_) & 63, wsrc = (wg + SH_) & 63;
    size_t src = ((size_t)b << 12) + (hs << 6) + wsrc;
    float4 v = *(const float4*)&x[src * C_ + lane * 4];
    float s = v.x + v.y + v.z + v.w;
    float s2 = v.x * v.x + v.y * v.y + v.z * v.z + v.w * v.w;
#pragma unroll
    for (int m = 1; m < 64; m <<= 1) { s += __shfl_xor(s, m); s2 += __shfl_xor(s2, m); }
    float mu = s * (1.f / 256.f);
    float rstd = rsqrtf(s2 * (1.f / 256.f) - mu * mu + LN_EPS);
    float4 sc = *(const float4*)&ss[b * 512 + lane * 4];
    float4 sh = *(const float4*)&ss[b * 512 + 256 + lane * 4];
    int win = (b << 6) + ((hg >> 3) << 3) + (wg >> 3);
    int pos = ((hg & 7) << 3) + (wg & 7);
    ushort4 pk;
    pk.x = f2b((v.x - mu) * rstd * (1.f + sc.x) + sh.x);
    pk.y = f2b((v.y - mu) * rstd * (1.f + sc.y) + sh.y);
    pk.z = f2b((v.z - mu) * rstd * (1.f + sc.z) + sh.z);
    pk.w = f2b((v.w - mu) * rstd * (1.f + sc.w) + sh.w);
    *(ushort4*)(xw + (size_t)(win * 64 + pos) * C_ + lane * 4) = pk;
}

// ---- bf16 MFMA GEMM v3 (R10): A one-shot LDS per 256-K chunk, B from L2 ----
// 8 waves = 2(M) x 4(N); per-wave 64x64 output (acc[4][4]); BM=128, BN=256.
// A: staged via global_load_lds, 64KB/chunk, XOR swizzle c^(row&7) applied on
// the GLOBAL source (rule 21: dest stays linear), reads use the same XOR ->
// 2-way max conflict (free). B: global_load_dwordx4 straight to frags (weight
// panel is L2/L1-hot; no LDS round-trip). NO barriers inside the k-loop; one
// stage+barrier per 256-K chunk (double-buffered when KDIM>256).
// MODE 0: QKV -> permuted bf16 + bias; MODE 1: O-proj -> window-reverse +
// fp32 residual + FUSED LN2/modulate (writes xn2 bf16; replaces ln_k);
// MODE 2: FFN1 -> gelu bf16; MODE 3: FFN2 -> fp32 residual.
template <int KDIM, int MODE, int NT>
__global__ __launch_bounds__(512, 2) void gemmv_k(
    const unsigned short* __restrict__ A, const unsigned short* __restrict__ Bt,
    const float* __restrict__ bias, const float* __restrict__ res,
    void* __restrict__ Cout, const float* __restrict__ ss2,
    unsigned short* __restrict__ xn2out, int Nout) {
    constexpr int NCH = KDIM / 256;
    constexpr int NBUF = (NCH > 1) ? 2 : 1;
    __shared__ __align__(16) unsigned short As[NBUF][128 * 256];

    const int blk = blockIdx.x;
    const int xcd = blk & 7;
    const int idx = blk >> 3;
    const int mt = xcd + ((idx / NT) << 3);
    const int nt = idx % NT;
    const int bm = mt * 128, bn = nt * 256;
    const int tid = threadIdx.x;
    const int w = tid >> 6, lane = tid & 63;
    const int quad = lane >> 4, l16 = lane & 15;
    const int wrow = (w >> 2) * 64;          // 0 or 64
    const int wcol = (w & 3) * 64;           // 0,64,128,192
    const int srow16 = tid >> 5;             // 0..15 (staging row within 16)
    const int sc = tid & 31;                 // staging 16B chunk in row

    f32x4 acc[4][4] = {};

    auto stageA = [&](int buf, int kc) {
#pragma unroll
        for (int p = 0; p < 8; ++p) {
            int row = p * 16 + srow16;
            int g = sc ^ (row & 7);          // inverse swizzle on global source
            const unsigned short* ga = A + (size_t)(bm + row) * KDIM + kc * 256 + g * 8;
            unsigned short* la = &As[buf][row * 256 + sc * 8];
            __builtin_amdgcn_global_load_lds(
                (const __attribute__((address_space(1))) void*)ga,
                (__attribute__((address_space(3))) void*)la, 16, 0, 0);
        }
    };

    auto computeC = [&](int buf, int kc) {
        const unsigned short* bp = Bt + (size_t)(bn + wcol + l16) * KDIM + kc * 256 + quad * 8;
#pragma unroll
        for (int k8 = 0; k8 < 8; ++k8) {
            bf16x8 bfr[4], af[4];
#pragma unroll
            for (int j = 0; j < 4; ++j)
                bfr[j] = *(const bf16x8*)(bp + (size_t)j * 16 * KDIM + k8 * 32);
#pragma unroll
            for (int i = 0; i < 4; ++i) {
                int row = wrow + i * 16 + l16;
                int cidx = (k8 * 4 + quad) ^ (row & 7);
                af[i] = *(const bf16x8*)&As[buf][row * 256 + cidx * 8];
            }
            __builtin_amdgcn_s_setprio(1);
#pragma unroll
            for (int i = 0; i < 4; ++i)
#pragma unroll
                for (int j = 0; j < 4; ++j)
                    acc[i][j] = __builtin_amdgcn_mfma_f32_16x16x32_bf16(
                        bfr[j], af[i], acc[i][j], 0, 0, 0);
            __builtin_amdgcn_s_setprio(0);
        }
    };

    stageA(0, 0);
    asm volatile("s_waitcnt vmcnt(0)" ::: "memory");
    __builtin_amdgcn_s_barrier();
    if constexpr (NCH == 1) {
        computeC(0, 0);
    } else {
#pragma unroll
        for (int c = 0; c < NCH; ++c) {
            if (c + 1 < NCH) stageA((c + 1) & 1, c + 1);   // issue-early (T14)
            computeC(c & 1, c);
            if (c + 1 < NCH) {
                asm volatile("s_waitcnt vmcnt(0)" ::: "memory");
                __builtin_amdgcn_s_barrier();
            }
        }
    }

    if (MODE == 1) {
        // -------- epilogue with fused residual + LayerNorm2 + modulate ------
        float ps[4], ps2[4];
#pragma unroll
        for (int i = 0; i < 4; ++i) {
            const int row = bm + wrow + i * 16 + l16;
            int win = row >> 6, pos = row & 63;
            int b = win >> 6, wh = (win >> 3) & 7, ww = win & 7;
            int hg = (wh << 3) + (pos >> 3), wg = (ww << 3) + (pos & 7);
            int hd = (hg + SH_) & 63, wd = (wg + SH_) & 63;
            size_t rowbase = (((size_t)b << 12) + (hd << 6) + wd) * C_;
            float s = 0.f, s2 = 0.f;
#pragma unroll
            for (int j = 0; j < 4; ++j) {
                const int col = bn + wcol + j * 16 + quad * 4;
                float4 bv = *(const float4*)&bias[col];
                float4 rv = *(const float4*)&res[rowbase + col];
                float4 ov = {acc[i][j][0] + bv.x + rv.x, acc[i][j][1] + bv.y + rv.y,
                             acc[i][j][2] + bv.z + rv.z, acc[i][j][3] + bv.w + rv.w};
                *(float4*)&((float*)Cout)[rowbase + col] = ov;
                acc[i][j][0] = ov.x; acc[i][j][1] = ov.y;
                acc[i][j][2] = ov.z; acc[i][j][3] = ov.w;
                s += ov.x + ov.y + ov.z + ov.w;
                s2 += ov.x * ov.x + ov.y * ov.y + ov.z * ov.z + ov.w * ov.w;
            }
            ps[i] = s; ps2[i] = s2;
        }
#pragma unroll
        for (int i = 0; i < 4; ++i) {
            ps[i] += __shfl_xor(ps[i], 16);  ps[i] += __shfl_xor(ps[i], 32);
            ps2[i] += __shfl_xor(ps2[i], 16); ps2[i] += __shfl_xor(ps2[i], 32);
        }
        float* sred = (float*)&As[0][0];     // [8 waves][64 rows][2] = 4 KB
        asm volatile("s_waitcnt lgkmcnt(0)" ::: "memory");
        __builtin_amdgcn_s_barrier();
        if (quad == 0) {
#pragma unroll
            for (int i = 0; i < 4; ++i) {
                int r = i * 16 + l16;
                sred[(w * 64 + r) * 2 + 0] = ps[i];
                sred[(w * 64 + r) * 2 + 1] = ps2[i];
            }
        }
        __builtin_amdgcn_s_barrier();
#pragma unroll
        for (int i = 0; i < 4; ++i) {
            int r = i * 16 + l16;
            float s = 0.f, s2 = 0.f;
#pragma unroll
            for (int cw = 0; cw < 4; ++cw) {
                s  += sred[(((w >> 2) * 4 + cw) * 64 + r) * 2 + 0];
                s2 += sred[(((w >> 2) * 4 + cw) * 64 + r) * 2 + 1];
            }
            float mu = s * (1.f / 256.f);
            float rstd = rsqrtf(s2 * (1.f / 256.f) - mu * mu + LN_EPS);
            const int row = bm + wrow + i * 16 + l16;
            int win = row >> 6, pos = row & 63;
            int b = win >> 6, wh = (win >> 3) & 7, ww = win & 7;
            int hg = (wh << 3) + (pos >> 3), wg = (ww << 3) + (pos & 7);
            int hd = (hg + SH_) & 63, wd = (wg + SH_) & 63;
            size_t rowbase = (((size_t)b << 12) + (hd << 6) + wd) * C_;
#pragma unroll
            for (int j = 0; j < 4; ++j) {
                const int col = bn + wcol + j * 16 + quad * 4;
                float4 scv = *(const float4*)&ss2[b * 512 + col];
                float4 shv = *(const float4*)&ss2[b * 512 + 256 + col];
                ushort4 pk;
                pk.x = f2b((acc[i][j][0] - mu) * rstd * (1.f + scv.x) + shv.x);
                pk.y = f2b((acc[i][j][1] - mu) * rstd * (1.f + scv.y) + shv.y);
                pk.z = f2b((acc[i][j][2] - mu) * rstd * (1.f + scv.z) + shv.z);
                pk.w = f2b((acc[i][j][3] - mu) * rstd * (1.f + scv.w) + shv.w);
                *(ushort4*)(xn2out + rowbase + col) = pk;
            }
        }
        return;
    }

#pragma unroll
    for (int i = 0; i < 4; ++i) {
        const int row = bm + wrow + i * 16 + l16;
        size_t rowbase = 0;
        if (MODE == 0) {
            int win = row >> 6, pos = row & 63;
            rowbase = (size_t)win * 16384 + pos * 32;
        } else {
            rowbase = (size_t)row * Nout;
        }
#pragma unroll
        for (int j = 0; j < 4; ++j) {
            const int col = bn + wcol + j * 16 + quad * 4;
            float4 bv = *(const float4*)&bias[col];
            float v0 = acc[i][j][0] + bv.x, v1 = acc[i][j][1] + bv.y;
            float v2 = acc[i][j][2] + bv.z, v3 = acc[i][j][3] + bv.w;
            if (MODE == 0) {
                int which = col >> 8, head = (col >> 5) & 7, dc = col & 31;
                ushort4 pk = {f2b(v0), f2b(v1), f2b(v2), f2b(v3)};
                *(ushort4*)((unsigned short*)Cout + (size_t)which * SL_ + rowbase +
                            head * 2048 + dc) = pk;
            } else if (MODE == 2) {
                ushort4 pk = {f2b(gelu_f(v0)), f2b(gelu_f(v1)),
                              f2b(gelu_f(v2)), f2b(gelu_f(v3))};
                *(ushort4*)((unsigned short*)Cout + rowbase + col) = pk;
            } else {
                float4 rv = *(const float4*)&res[rowbase + col];
                float4 ov = {v0 + rv.x, v1 + rv.y, v2 + rv.z, v3 + rv.w};
                *(float4*)&((float*)Cout)[rowbase + col] = ov;
            }
        }
    }
}

// ------------- MFMA window attention: one wave per (window, head) ------------
__global__ __launch_bounds__(256) void attn_mfma_k(
    const unsigned short* __restrict__ qkv, const float* __restrict__ bias_full,
    unsigned short* __restrict__ attn_out) {
    __shared__ __align__(16) unsigned short Pb[4][64 * 66];
    __shared__ __align__(16) unsigned short Vt[4][32 * 66];
    const int w = threadIdx.x >> 6, lane = threadIdx.x & 63;
    const int wh = blockIdx.x * 4 + w;        // 0..4095
    const int win = wh >> 3, head = wh & 7;
    const int quad = lane >> 4, l16 = lane & 15;

    const unsigned short* qp = qkv + (size_t)win * 16384 + head * 2048;
    const unsigned short* kp = qp + SL_;
    const unsigned short* vp = qp + 2 * (size_t)SL_;

    // stage V transposed: Vt[d][pos]
    {
        const uint4* v4 = (const uint4*)(vp + lane * 32);
        unsigned short* dst = &Vt[w][0];
#pragma unroll
        for (int c = 0; c < 4; ++c) {
            uint4 u = v4[c];
            unsigned int uu[4] = {u.x, u.y, u.z, u.w};
#pragma unroll
            for (int p = 0; p < 4; ++p) {
                int d0 = c * 8 + p * 2;
                dst[d0 * 66 + lane] = (unsigned short)(uu[p] & 0xffff);
                dst[(d0 + 1) * 66 + lane] = (unsigned short)(uu[p] >> 16);
            }
        }
    }

    bf16x8 qf[4], kf[4];
#pragma unroll
    for (int i = 0; i < 4; ++i) {
        qf[i] = *(const bf16x8*)(qp + (i * 16 + l16) * 32 + quad * 8);
        kf[i] = *(const bf16x8*)(kp + (i * 16 + l16) * 32 + quad * 8);
    }

    f32x4 s[4][4] = {};
#pragma unroll
    for (int i = 0; i < 4; ++i)
#pragma unroll
        for (int j = 0; j < 4; ++j)
            s[i][j] = __builtin_amdgcn_mfma_f32_16x16x32_bf16(qf[i], kf[j], s[i][j], 0, 0, 0);

    const float scale = 0.17677669529663687f;
    const float* bf = bias_full + head * 4096;
    float rs[4][4];
#pragma unroll
    for (int i = 0; i < 4; ++i) {
#pragma unroll
        for (int r = 0; r < 4; ++r) {
            int row = i * 16 + quad * 4 + r;
            float acc = 0.f;
#pragma unroll
            for (int j = 0; j < 4; ++j) {
                float e = __expf(s[i][j][r] * scale + bf[row * 64 + j * 16 + l16]);
                s[i][j][r] = e;
                acc += e;
            }
#pragma unroll
            for (int msk = 1; msk < 16; msk <<= 1) acc += __shfl_xor(acc, msk);
            rs[i][r] = 1.f / acc;
        }
    }

#pragma unroll
    for (int i = 0; i < 4; ++i)
#pragma unroll
        for (int j = 0; j < 4; ++j)
#pragma unroll
            for (int r = 0; r < 4; ++r)
                Pb[w][(i * 16 + quad * 4 + r) * 66 + j * 16 + l16] = f2b(s[i][j][r]);

    __syncthreads();

    f32x4 o[4][2] = {};
#pragma unroll
    for (int st = 0; st < 2; ++st) {
        bf16x8 bv[2];
#pragma unroll
        for (int jo = 0; jo < 2; ++jo)
            bv[jo] = *(const bf16x8*)&Vt[w][(jo * 16 + l16) * 66 + st * 32 + quad * 8];
#pragma unroll
        for (int i = 0; i < 4; ++i) {
            bf16x8 af = *(const bf16x8*)&Pb[w][(i * 16 + l16) * 66 + st * 32 + quad * 8];
#pragma unroll
            for (int jo = 0; jo < 2; ++jo)
                o[i][jo] = __builtin_amdgcn_mfma_f32_16x16x32_bf16(af, bv[jo], o[i][jo], 0, 0, 0);
        }
    }

#pragma unroll
    for (int i = 0; i < 4; ++i)
#pragma unroll
        for (int jo = 0; jo < 2; ++jo)
#pragma unroll
            for (int r = 0; r < 4; ++r) {
                int row = i * 16 + quad * 4 + r;
                int d = jo * 16 + l16;
                attn_out[((size_t)(win * 64 + row)) * C_ + head * 32 + d] =
                    f2b(o[i][jo][r] * rs[i][r]);
            }
}

extern "C" void kernel_launch(void* const* d_in, const int* in_sizes, int n_in,
                              void* d_out, int out_size, void* d_ws, size_t ws_size,
                              hipStream_t stream) {
    const float* x        = (const float*)d_in[0];
    const float* t_embed  = (const float*)d_in[1];
    const float* adaln1_w = (const float*)d_in[4];
    const float* adaln1_b = (const float*)d_in[5];
    const float* adaln2_w = (const float*)d_in[6];
    const float* adaln2_b = (const float*)d_in[7];
    const float* bt       = (const float*)d_in[8];
    const float* q_w = (const float*)d_in[9],  *q_b = (const float*)d_in[10];
    const float* k_w = (const float*)d_in[11], *k_b = (const float*)d_in[12];
    const float* v_w = (const float*)d_in[13], *v_b = (const float*)d_in[14];
    const float* o_w = (const float*)d_in[15], *o_b = (const float*)d_in[16];
    const float* f1_w = (const float*)d_in[17], *f1_b = (const float*)d_in[18];
    const float* f2_w = (const float*)d_in[19], *f2_b = (const float*)d_in[20];
    float* out = (float*)d_out;

    char* wsb = (char*)d_ws;
    float* ss1            = (float*)(wsb + 0);
    float* ss2            = (float*)(wsb + 16384);
    float* qkvB           = (float*)(wsb + 32768);
    unsigned short* qkvT  = (unsigned short*)(wsb + 36864);
    unsigned short* oT    = (unsigned short*)(wsb + 430080);
    unsigned short* f1T   = (unsigned short*)(wsb + 561152);
    unsigned short* f2T   = (unsigned short*)(wsb + 1085440);
    float* bias_full      = (float*)(wsb + 1609728);               // 131072 B
    unsigned short* xw    = (unsigned short*)(wsb + 2097152);      // [M][256] bf16
    unsigned short* qkv   = (unsigned short*)(wsb + 18874368);     // 3 x SL_ bf16
    unsigned short* attn  = (unsigned short*)(wsb + 69206016);     // [M][256] bf16
    unsigned short* xn2   = xw;                                    // reuse
    unsigned short* hbuf  = qkv;                                   // reuse (67.1 MB)
    float* x1             = (float*)(wsb + 85983232);              // [M][256] fp32

    prep_k<<<3235, 256, 0, stream>>>(q_w, k_w, v_w, o_w, f1_w, f2_w, q_b, k_b, v_b, bt,
                                     t_embed, adaln1_w, adaln1_b, adaln2_w, adaln2_b,
                                     qkvT, oT, f1T, f2T, qkvB, bias_full, ss1, ss2);
    ln_win_k<<<8192, 256, 0, stream>>>(x, ss1, xw);

    // QKV: 256 mt x 3 nt = 768 blocks (3/CU)
    gemmv_k<256, 0, 3><<<768, 512, 0, stream>>>(xw, qkvT, qkvB, nullptr, qkv,
                                                nullptr, nullptr, 768);

    attn_mfma_k<<<1024, 256, 0, stream>>>(qkv, bias_full, attn);

    // O-proj + residual + fused LN2/modulate: 256 mt x 1 nt = 256 blocks
    gemmv_k<256, 1, 1><<<256, 512, 0, stream>>>(attn, oT, o_b, x, x1,
                                                ss2, xn2, 256);
    // FFN1: 256 mt x 4 nt = 1024 blocks (4/CU)
    gemmv_k<256, 2, 4><<<1024, 512, 0, stream>>>(xn2, f1T, f1_b, nullptr, hbuf,
                                                 nullptr, nullptr, 1024);
    // FFN2: K=1024 (4 chunks, dbuf), 256 blocks
    gemmv_k<1024, 3, 1><<<256, 512, 0, stream>>>(hbuf, f2T, f2_b, x1, out,
                                                 nullptr, nullptr, 256);
}

// Round 4
// 300.644 us; speedup vs baseline: 1.0558x; 1.0558x over previous
//
#include <hip/hip_runtime.h>
#include <math.h>

#define WS_ 8
#define NH_ 8
#define C_ 256
#define B_ 8
#define M_ 32768            // B_*L_
#define SH_ 4               // WS_/2
#define LN_EPS 1e-5f
#define SL_ 8388608         // elements per [M,C] slot

typedef __attribute__((ext_vector_type(8))) short bf16x8;
typedef __attribute__((ext_vector_type(4))) float f32x4;

__device__ inline float b2f(unsigned short u) {
    union { unsigned int i; float f; } c; c.i = ((unsigned int)u) << 16; return c.f;
}
__device__ inline unsigned short f2b(float f) {
    union { unsigned int i; float f; } c; c.f = f;
    unsigned int u = c.i;
    return (unsigned short)((u + 0x7FFFu + ((u >> 16) & 1u)) >> 16);
}
__device__ inline float gelu_f(float x) {
    // tanh-form GELU: x * sigmoid(1.59576912*(x + 0.044715 x^3)); |err| < ~1e-3
    float t = 1.59576912160573f * (x + 0.044715f * x * x * x);
    return x / (1.f + __expf(-t));
}

// ---------- weight prep + adaln fused: bf16 [N][K] transposes, qkv bias,
// ---------- bias_full, and ss = t_embed @ w + b for both adaln layers -------
__global__ void prep_k(const float* __restrict__ qw, const float* __restrict__ kw,
                       const float* __restrict__ vw, const float* __restrict__ ow,
                       const float* __restrict__ f1w, const float* __restrict__ f2w,
                       const float* __restrict__ qb, const float* __restrict__ kb,
                       const float* __restrict__ vb, const float* __restrict__ bt,
                       const float* __restrict__ te,
                       const float* __restrict__ a1w, const float* __restrict__ a1b,
                       const float* __restrict__ a2w, const float* __restrict__ a2b,
                       unsigned short* __restrict__ qkvT, unsigned short* __restrict__ oT,
                       unsigned short* __restrict__ f1T, unsigned short* __restrict__ f2T,
                       float* __restrict__ qkvB, float* __restrict__ bias_full,
                       float* __restrict__ ss1, float* __restrict__ ss2) {
    int t = blockIdx.x * 256 + threadIdx.x;
    if (t < 196608) {                       // qkvT [768][256]
        int n = t >> 8, k = t & 255;
        const float* w = n < 256 ? qw : (n < 512 ? kw : vw);
        qkvT[t] = f2b(w[k * 256 + (n & 255)]);
    } else if (t < 262144) {                // oT [256][256]
        int i = t - 196608; int n = i >> 8, k = i & 255;
        oT[i] = f2b(ow[k * 256 + n]);
    } else if (t < 524288) {                // f1T [1024][256]
        int i = t - 262144; int n = i >> 8, k = i & 255;
        f1T[i] = f2b(f1w[k * 1024 + n]);
    } else if (t < 786432) {                // f2T [256][1024]
        int i = t - 524288; int n = i >> 10, k = i & 1023;
        f2T[i] = f2b(f2w[k * 256 + n]);
    } else if (t < 787200) {                // qkv bias [768]
        int i = t - 786432;
        qkvB[i] = i < 256 ? qb[i] : (i < 512 ? kb[i - 256] : vb[i - 512]);
    } else if (t < 819968) {                // bias_full [8][64][64]
        int i = t - 787200;
        int head = i >> 12, qk = i & 4095;
        int q = qk >> 6, k = qk & 63;
        int qh = q >> 3, qw2 = q & 7, kh = k >> 3, kw2 = k & 7;
        bias_full[i] = bt[((qh - kh + 7) * 15 + (qw2 - kw2 + 7)) * 8 + head];
    } else if (t < 828160) {                // adaln: 2 x [8][512]
        int i = t - 819968;
        int which = i >> 12;
        int rem = i & 4095;
        int b = rem >> 9, col = rem & 511;
        const float* w = which ? a2w : a1w;
        const float* bb = which ? a2b : a1b;
        const float* tr = te + b * C_;
        float acc = bb[col];
        for (int k = 0; k < C_; ++k) acc += tr[k] * w[k * 512 + col];
        (which ? ss2 : ss1)[b * 512 + col] = acc;
    }
}

// ------ LN + modulate + shift + window partition: one wave per token ---------
__global__ __launch_bounds__(256) void ln_win_k(const float* __restrict__ x,
                                                const float* __restrict__ ss,
                                                unsigned short* __restrict__ xw) {
    int t = blockIdx.x * 4 + (threadIdx.x >> 6);     // token 0..32767
    int lane = threadIdx.x & 63;
    int b = t >> 12, rem = t & 4095;
    int hg = rem >> 6, wg = rem & 63;
    int hs = (hg + SH_) & 63, wsrc = (wg + SH_) & 63;
    size_t src = ((size_t)b << 12) + (hs << 6) + wsrc;
    float4 v = *(const float4*)&x[src * C_ + lane * 4];
    float s = v.x + v.y + v.z + v.w;
    float s2 = v.x * v.x + v.y * v.y + v.z * v.z + v.w * v.w;
#pragma unroll
    for (int m = 1; m < 64; m <<= 1) { s += __shfl_xor(s, m); s2 += __shfl_xor(s2, m); }
    float mu = s * (1.f / 256.f);
    float rstd = rsqrtf(s2 * (1.f / 256.f) - mu * mu + LN_EPS);
    float4 sc = *(const float4*)&ss[b * 512 + lane * 4];
    float4 sh = *(const float4*)&ss[b * 512 + 256 + lane * 4];
    int win = (b << 6) + ((hg >> 3) << 3) + (wg >> 3);
    int pos = ((hg & 7) << 3) + (wg & 7);
    ushort4 pk;
    pk.x = f2b((v.x - mu) * rstd * (1.f + sc.x) + sh.x);
    pk.y = f2b((v.y - mu) * rstd * (1.f + sc.y) + sh.y);
    pk.z = f2b((v.z - mu) * rstd * (1.f + sc.z) + sh.z);
    pk.w = f2b((v.w - mu) * rstd * (1.f + sc.w) + sh.w);
    *(ushort4*)(xw + (size_t)(win * 64 + pos) * C_ + lane * 4) = pk;
}

// ---------------- LN + modulate: one wave per token --------------------------
__global__ __launch_bounds__(256) void ln_k(const float* __restrict__ x,
                                            const float* __restrict__ ss,
                                            unsigned short* __restrict__ y_out) {
    int t = blockIdx.x * 4 + (threadIdx.x >> 6);
    int lane = threadIdx.x & 63;
    int b = t >> 12;
    float4 v = *(const float4*)&x[(size_t)t * C_ + lane * 4];
    float s = v.x + v.y + v.z + v.w;
    float s2 = v.x * v.x + v.y * v.y + v.z * v.z + v.w * v.w;
#pragma unroll
    for (int m = 1; m < 64; m <<= 1) { s += __shfl_xor(s, m); s2 += __shfl_xor(s2, m); }
    float mu = s * (1.f / 256.f);
    float rstd = rsqrtf(s2 * (1.f / 256.f) - mu * mu + LN_EPS);
    float4 sc = *(const float4*)&ss[b * 512 + lane * 4];
    float4 sh = *(const float4*)&ss[b * 512 + 256 + lane * 4];
    ushort4 pk;
    pk.x = f2b((v.x - mu) * rstd * (1.f + sc.x) + sh.x);
    pk.y = f2b((v.y - mu) * rstd * (1.f + sc.y) + sh.y);
    pk.z = f2b((v.z - mu) * rstd * (1.f + sc.z) + sh.z);
    pk.w = f2b((v.w - mu) * rstd * (1.f + sc.w) + sh.w);
    *(ushort4*)(y_out + (size_t)t * C_ + lane * 4) = pk;
}

// --------------- bf16 MFMA GEMM, 128x128 tile, BK=64, swizzled LDS -----------
// R0-exact template (best measured; 0 bank conflicts). Used for QKV / O-proj.
// MODE 0: QKV -> permuted bf16 + bias; MODE 1: O-proj -> window-reverse +
// fp32 residual.
template <int KDIM, int MODE, int NT, int MINW>
__global__ __launch_bounds__(256, MINW) void gemm_bf16_k(
    const unsigned short* __restrict__ A, const unsigned short* __restrict__ Bt,
    const float* __restrict__ bias, const float* __restrict__ res,
    void* __restrict__ Cout, int Nout) {
    __shared__ __align__(16) unsigned short As[2][128 * 32];
    __shared__ __align__(16) unsigned short Bs[2][128 * 32];
    const int blk = blockIdx.x;
    const int xcd = blk & 7;
    const int idx = blk >> 3;
    const int mt = xcd + ((idx / NT) << 3);
    const int nt = idx % NT;
    const int bm = mt * 128, bn = nt * 128;
    const int tid = threadIdx.x;
    const int w = tid >> 6, lane = tid & 63;
    const int quad = lane >> 4, l16 = lane & 15;
    const int wm = (w >> 1) * 64, wn = (w & 1) * 64;
    const int srow = lane >> 2;
    const int qlog = ((lane & 3) ^ ((lane >> 3) & 3)) << 3;
    const int rsw = ((l16 >> 1) & 3) << 3;

    f32x4 acc[4][4] = {};

    for (int k0 = 0; k0 < KDIM; k0 += 64) {
        if (k0) __syncthreads();
#pragma unroll
        for (int h = 0; h < 2; ++h) {
#pragma unroll
            for (int j = 0; j < 2; ++j) {
                int r = j * 64 + w * 16 + srow;
                const unsigned short* ga = A + (size_t)(bm + r) * KDIM + k0 + h * 32 + qlog;
                unsigned short* la = &As[h][j * 2048 + w * 512 + lane * 8];
                __builtin_amdgcn_global_load_lds(
                    (const __attribute__((address_space(1))) void*)ga,
                    (__attribute__((address_space(3))) void*)la, 16, 0, 0);
                const unsigned short* gb = Bt + (size_t)(bn + r) * KDIM + k0 + h * 32 + qlog;
                unsigned short* lb = &Bs[h][j * 2048 + w * 512 + lane * 8];
                __builtin_amdgcn_global_load_lds(
                    (const __attribute__((address_space(1))) void*)gb,
                    (__attribute__((address_space(3))) void*)lb, 16, 0, 0);
            }
        }
        __syncthreads();
#pragma unroll
        for (int h = 0; h < 2; ++h) {
            bf16x8 af[4], bfr[4];
#pragma unroll
            for (int i = 0; i < 4; ++i)
                af[i] = *(const bf16x8*)&As[h][(wm + i * 16 + l16) * 32 + ((quad << 3) ^ rsw)];
#pragma unroll
            for (int j = 0; j < 4; ++j)
                bfr[j] = *(const bf16x8*)&Bs[h][(wn + j * 16 + l16) * 32 + ((quad << 3) ^ rsw)];
#pragma unroll
            for (int i = 0; i < 4; ++i)
#pragma unroll
                for (int j = 0; j < 4; ++j)
                    acc[i][j] = __builtin_amdgcn_mfma_f32_16x16x32_bf16(
                        bfr[j], af[i], acc[i][j], 0, 0, 0);
        }
    }

#pragma unroll
    for (int i = 0; i < 4; ++i) {
        const int row = bm + wm + i * 16 + l16;
        size_t rowbase = 0;
        if (MODE == 0) {
            int win = row >> 6, pos = row & 63;
            rowbase = (size_t)win * 16384 + pos * 32;
        } else if (MODE == 1) {
            int win = row >> 6, pos = row & 63;
            int b = win >> 6, wh = (win >> 3) & 7, ww = win & 7;
            int hg = (wh << 3) + (pos >> 3), wg = (ww << 3) + (pos & 7);
            int hd = (hg + SH_) & 63, wd = (wg + SH_) & 63;
            rowbase = (((size_t)b << 12) + (hd << 6) + wd) * C_;
        } else {
            rowbase = (size_t)row * Nout;
        }
#pragma unroll
        for (int j = 0; j < 4; ++j) {
            const int col = bn + wn + j * 16 + quad * 4;
            float4 bv = *(const float4*)&bias[col];
            float v0 = acc[i][j][0] + bv.x, v1 = acc[i][j][1] + bv.y;
            float v2 = acc[i][j][2] + bv.z, v3 = acc[i][j][3] + bv.w;
            if (MODE == 0) {
                int which = col >> 8, head = (col >> 5) & 7, dc = col & 31;
                ushort4 pk = {f2b(v0), f2b(v1), f2b(v2), f2b(v3)};
                *(ushort4*)((unsigned short*)Cout + (size_t)which * SL_ + rowbase +
                            head * 2048 + dc) = pk;
            } else if (MODE == 1) {
                float4 rv = *(const float4*)&res[rowbase + col];
                float4 ov = {v0 + rv.x, v1 + rv.y, v2 + rv.z, v3 + rv.w};
                *(float4*)&((float*)Cout)[rowbase + col] = ov;
            } else if (MODE == 2) {
                ushort4 pk = {f2b(gelu_f(v0)), f2b(gelu_f(v1)),
                              f2b(gelu_f(v2)), f2b(gelu_f(v3))};
                *(ushort4*)((unsigned short*)Cout + rowbase + col) = pk;
            } else {
                float4 rv = *(const float4*)&res[rowbase + col];
                float4 ov = {v0 + rv.x, v1 + rv.y, v2 + rv.z, v3 + rv.w};
                *(float4*)&((float*)Cout)[rowbase + col] = ov;
            }
        }
    }
}

// ------------- fused FFN: out = gelu(xn2@f1+b1)@f2 + b2 + x1 (R11) -----------
// 64 rows/block, 8 waves. Phase 1: wave w computes h[64][w*128..+128) via
// MFMA (A-frags from global - 32KB tile is L1-hot across waves; B-frags = f1T
// rows, L2-hot 0.5MB shared by all blocks, register-reused over i), gelu,
// packs bf16x4, ds_write_b64 into hs with 16B-chunk XOR swizzle c^=(row&7)
// (writes are aligned 8B halves of a chunk; XOR at chunk granularity keeps
// both halves together -> read side gets whole 16B chunks). One barrier.
// Phase 2: out cols w*32..+32, K=1024: A-frags (h) from LDS swizzled,
// B-frags = f2T rows from L2, accumulate in regs, epilogue adds b2 + x1.
// Eliminates the 64MB hbuf write + 67MB read of the split FFN1/FFN2 path.
__global__ __launch_bounds__(512, 2) void ffn_fused_k(
    const unsigned short* __restrict__ xn2, const unsigned short* __restrict__ f1T,
    const unsigned short* __restrict__ f2T, const float* __restrict__ f1b,
    const float* __restrict__ f2bias, const float* __restrict__ x1,
    float* __restrict__ out) {
    __shared__ __align__(16) unsigned short hs[64 * 1024];   // 128 KB
    const int tid = threadIdx.x;
    const int w = tid >> 6, lane = tid & 63;
    const int quad = lane >> 4, l16 = lane & 15;
    const int brow = blockIdx.x * 64;

    // ---------------- phase 1: h = gelu(xn2 @ f1 + b1) ----------------------
    {
        f32x4 acc[4][8] = {};
        const unsigned short* ap = xn2 + (size_t)(brow + l16) * 256 + quad * 8;
        const unsigned short* bp = f1T + (size_t)(w * 128 + l16) * 256 + quad * 8;
#pragma unroll
        for (int k = 0; k < 8; ++k) {
            bf16x8 ax[4], bf1[8];
#pragma unroll
            for (int i = 0; i < 4; ++i)
                ax[i] = *(const bf16x8*)(ap + (size_t)i * 16 * 256 + k * 32);
#pragma unroll
            for (int j = 0; j < 8; ++j)
                bf1[j] = *(const bf16x8*)(bp + (size_t)j * 16 * 256 + k * 32);
            __builtin_amdgcn_s_setprio(1);
#pragma unroll
            for (int i = 0; i < 4; ++i)
#pragma unroll
                for (int j = 0; j < 8; ++j)
                    acc[i][j] = __builtin_amdgcn_mfma_f32_16x16x32_bf16(
                        bf1[j], ax[i], acc[i][j], 0, 0, 0);
            __builtin_amdgcn_s_setprio(0);
        }
#pragma unroll
        for (int i = 0; i < 4; ++i) {
            int row = i * 16 + l16;
#pragma unroll
            for (int j = 0; j < 8; ++j) {
                int col = w * 128 + j * 16 + quad * 4;
                float4 bv = *(const float4*)&f1b[col];
                ushort4 pk;
                pk.x = f2b(gelu_f(acc[i][j][0] + bv.x));
                pk.y = f2b(gelu_f(acc[i][j][1] + bv.y));
                pk.z = f2b(gelu_f(acc[i][j][2] + bv.z));
                pk.w = f2b(gelu_f(acc[i][j][3] + bv.w));
                int c = col >> 3;                 // 16B chunk index (0..127)
                int half = (col >> 2) & 1;        // 8B half within chunk
                int cs = c ^ (row & 7);           // XOR swizzle (chunk-granular)
                *(ushort4*)&hs[row * 1024 + cs * 8 + half * 4] = pk;
            }
        }
    }
    __syncthreads();

    // ---------------- phase 2: out = h @ f2 + b2 + x1 -----------------------
    {
        f32x4 acc[4][2] = {};
        const unsigned short* bp = f2T + (size_t)(w * 32 + l16) * 1024 + quad * 8;
#pragma unroll
        for (int k = 0; k < 32; ++k) {
            bf16x8 ah[4], bf2[2];
#pragma unroll
            for (int jo = 0; jo < 2; ++jo)
                bf2[jo] = *(const bf16x8*)(bp + (size_t)jo * 16 * 1024 + k * 32);
#pragma unroll
            for (int i = 0; i < 4; ++i) {
                int row = i * 16 + l16;
                int c = (k * 4 + quad) ^ (row & 7);
                ah[i] = *(const bf16x8*)&hs[row * 1024 + c * 8];
            }
            __builtin_amdgcn_s_setprio(1);
#pragma unroll
            for (int i = 0; i < 4; ++i)
#pragma unroll
                for (int jo = 0; jo < 2; ++jo)
                    acc[i][jo] = __builtin_amdgcn_mfma_f32_16x16x32_bf16(
                        bf2[jo], ah[i], acc[i][jo], 0, 0, 0);
            __builtin_amdgcn_s_setprio(0);
        }
#pragma unroll
        for (int i = 0; i < 4; ++i) {
            int row = brow + i * 16 + l16;
#pragma unroll
            for (int jo = 0; jo < 2; ++jo) {
                int col = w * 32 + jo * 16 + quad * 4;
                float4 bv = *(const float4*)&f2bias[col];
                float4 rv = *(const float4*)&x1[(size_t)row * 256 + col];
                float4 ov = {acc[i][jo][0] + bv.x + rv.x, acc[i][jo][1] + bv.y + rv.y,
                             acc[i][jo][2] + bv.z + rv.z, acc[i][jo][3] + bv.w + rv.w};
                *(float4*)&out[(size_t)row * 256 + col] = ov;
            }
        }
    }
}

// ------------- MFMA window attention: one wave per (window, head) ------------
__global__ __launch_bounds__(256) void attn_mfma_k(
    const unsigned short* __restrict__ qkv, const float* __restrict__ bias_full,
    unsigned short* __restrict__ attn_out) {
    __shared__ __align__(16) unsigned short Pb[4][64 * 66];
    __shared__ __align__(16) unsigned short Vt[4][32 * 66];
    const int w = threadIdx.x >> 6, lane = threadIdx.x & 63;
    const int wh = blockIdx.x * 4 + w;        // 0..4095
    const int win = wh >> 3, head = wh & 7;
    const int quad = lane >> 4, l16 = lane & 15;

    const unsigned short* qp = qkv + (size_t)win * 16384 + head * 2048;
    const unsigned short* kp = qp + SL_;
    const unsigned short* vp = qp + 2 * (size_t)SL_;

    // stage V transposed: Vt[d][pos]
    {
        const uint4* v4 = (const uint4*)(vp + lane * 32);
        unsigned short* dst = &Vt[w][0];
#pragma unroll
        for (int c = 0; c < 4; ++c) {
            uint4 u = v4[c];
            unsigned int uu[4] = {u.x, u.y, u.z, u.w};
#pragma unroll
            for (int p = 0; p < 4; ++p) {
                int d0 = c * 8 + p * 2;
                dst[d0 * 66 + lane] = (unsigned short)(uu[p] & 0xffff);
                dst[(d0 + 1) * 66 + lane] = (unsigned short)(uu[p] >> 16);
            }
        }
    }

    bf16x8 qf[4], kf[4];
#pragma unroll
    for (int i = 0; i < 4; ++i) {
        qf[i] = *(const bf16x8*)(qp + (i * 16 + l16) * 32 + quad * 8);
        kf[i] = *(const bf16x8*)(kp + (i * 16 + l16) * 32 + quad * 8);
    }

    f32x4 s[4][4] = {};
#pragma unroll
    for (int i = 0; i < 4; ++i)
#pragma unroll
        for (int j = 0; j < 4; ++j)
            s[i][j] = __builtin_amdgcn_mfma_f32_16x16x32_bf16(qf[i], kf[j], s[i][j], 0, 0, 0);

    const float scale = 0.17677669529663687f;
    const float* bf = bias_full + head * 4096;
    float rs[4][4];
#pragma unroll
    for (int i = 0; i < 4; ++i) {
#pragma unroll
        for (int r = 0; r < 4; ++r) {
            int row = i * 16 + quad * 4 + r;
            float acc = 0.f;
#pragma unroll
            for (int j = 0; j < 4; ++j) {
                float e = __expf(s[i][j][r] * scale + bf[row * 64 + j * 16 + l16]);
                s[i][j][r] = e;
                acc += e;
            }
#pragma unroll
            for (int msk = 1; msk < 16; msk <<= 1) acc += __shfl_xor(acc, msk);
            rs[i][r] = 1.f / acc;
        }
    }

#pragma unroll
    for (int i = 0; i < 4; ++i)
#pragma unroll
        for (int j = 0; j < 4; ++j)
#pragma unroll
            for (int r = 0; r < 4; ++r)
                Pb[w][(i * 16 + quad * 4 + r) * 66 + j * 16 + l16] = f2b(s[i][j][r]);

    __syncthreads();

    f32x4 o[4][2] = {};
#pragma unroll
    for (int st = 0; st < 2; ++st) {
        bf16x8 bv[2];
#pragma unroll
        for (int jo = 0; jo < 2; ++jo)
            bv[jo] = *(const bf16x8*)&Vt[w][(jo * 16 + l16) * 66 + st * 32 + quad * 8];
#pragma unroll
        for (int i = 0; i < 4; ++i) {
            bf16x8 af = *(const bf16x8*)&Pb[w][(i * 16 + l16) * 66 + st * 32 + quad * 8];
#pragma unroll
            for (int jo = 0; jo < 2; ++jo)
                o[i][jo] = __builtin_amdgcn_mfma_f32_16x16x32_bf16(af, bv[jo], o[i][jo], 0, 0, 0);
        }
    }

#pragma unroll
    for (int i = 0; i < 4; ++i)
#pragma unroll
        for (int jo = 0; jo < 2; ++jo)
#pragma unroll
            for (int r = 0; r < 4; ++r) {
                int row = i * 16 + quad * 4 + r;
                int d = jo * 16 + l16;
                attn_out[((size_t)(win * 64 + row)) * C_ + head * 32 + d] =
                    f2b(o[i][jo][r] * rs[i][r]);
            }
}

extern "C" void kernel_launch(void* const* d_in, const int* in_sizes, int n_in,
                              void* d_out, int out_size, void* d_ws, size_t ws_size,
                              hipStream_t stream) {
    const float* x        = (const float*)d_in[0];
    const float* t_embed  = (const float*)d_in[1];
    const float* adaln1_w = (const float*)d_in[4];
    const float* adaln1_b = (const float*)d_in[5];
    const float* adaln2_w = (const float*)d_in[6];
    const float* adaln2_b = (const float*)d_in[7];
    const float* bt       = (const float*)d_in[8];
    const float* q_w = (const float*)d_in[9],  *q_b = (const float*)d_in[10];
    const float* k_w = (const float*)d_in[11], *k_b = (const float*)d_in[12];
    const float* v_w = (const float*)d_in[13], *v_b = (const float*)d_in[14];
    const float* o_w = (const float*)d_in[15], *o_b = (const float*)d_in[16];
    const float* f1_w = (const float*)d_in[17], *f1_b = (const float*)d_in[18];
    const float* f2_w = (const float*)d_in[19], *f2_b = (const float*)d_in[20];
    float* out = (float*)d_out;

    char* wsb = (char*)d_ws;
    float* ss1            = (float*)(wsb + 0);
    float* ss2            = (float*)(wsb + 16384);
    float* qkvB           = (float*)(wsb + 32768);
    unsigned short* qkvT  = (unsigned short*)(wsb + 36864);
    unsigned short* oT    = (unsigned short*)(wsb + 430080);
    unsigned short* f1T   = (unsigned short*)(wsb + 561152);
    unsigned short* f2T   = (unsigned short*)(wsb + 1085440);
    float* bias_full      = (float*)(wsb + 1609728);               // 131072 B
    unsigned short* xw    = (unsigned short*)(wsb + 2097152);      // [M][256] bf16
    unsigned short* qkv   = (unsigned short*)(wsb + 18874368);     // 3 x SL_ bf16
    unsigned short* attn  = (unsigned short*)(wsb + 69206016);     // [M][256] bf16
    unsigned short* xn2   = xw;                                    // reuse
    float* x1             = (float*)(wsb + 85983232);              // [M][256] fp32

    prep_k<<<3235, 256, 0, stream>>>(q_w, k_w, v_w, o_w, f1_w, f2_w, q_b, k_b, v_b, bt,
                                     t_embed, adaln1_w, adaln1_b, adaln2_w, adaln2_b,
                                     qkvT, oT, f1T, f2T, qkvB, bias_full, ss1, ss2);
    ln_win_k<<<8192, 256, 0, stream>>>(x, ss1, xw);

    gemm_bf16_k<256, 0, 6, 3><<<1536, 256, 0, stream>>>(xw, qkvT, qkvB, nullptr, qkv, 768);

    attn_mfma_k<<<1024, 256, 0, stream>>>(qkv, bias_full, attn);

    gemm_bf16_k<256, 1, 2, 1><<<512, 256, 0, stream>>>(attn, oT, o_b, x, x1, 256);
    ln_k<<<8192, 256, 0, stream>>>(x1, ss2, xn2);

    // fused FFN1+FFN2: 512 blocks x 64 rows, no hbuf round-trip
    ffn_fused_k<<<512, 512, 0, stream>>>(xn2, f1T, f2T, f1_b, f2_b, x1, out);
}

// Round 5
// 270.806 us; speedup vs baseline: 1.1722x; 1.1102x over previous
//
#include <hip/hip_runtime.h>
#include <math.h>

#define WS_ 8
#define NH_ 8
#define C_ 256
#define B_ 8
#define M_ 32768            // B_*L_
#define SH_ 4               // WS_/2
#define LN_EPS 1e-5f
#define SL_ 8388608         // elements per [M,C] slot

typedef __attribute__((ext_vector_type(8))) short bf16x8;
typedef __attribute__((ext_vector_type(4))) float f32x4;

__device__ inline float b2f(unsigned short u) {
    union { unsigned int i; float f; } c; c.i = ((unsigned int)u) << 16; return c.f;
}
__device__ inline unsigned short f2b(float f) {
    union { unsigned int i; float f; } c; c.f = f;
    unsigned int u = c.i;
    return (unsigned short)((u + 0x7FFFu + ((u >> 16) & 1u)) >> 16);
}
__device__ inline float gelu_f(float x) {
    // tanh-form GELU: x * sigmoid(1.59576912*(x + 0.044715 x^3)); |err| < ~1e-3
    float t = 1.59576912160573f * (x + 0.044715f * x * x * x);
    return x / (1.f + __expf(-t));
}

// ---------- weight prep + adaln fused: bf16 [N][K] transposes, qkv bias,
// ---------- bias_full, and ss = t_embed @ w + b for both adaln layers -------
__global__ void prep_k(const float* __restrict__ qw, const float* __restrict__ kw,
                       const float* __restrict__ vw, const float* __restrict__ ow,
                       const float* __restrict__ f1w, const float* __restrict__ f2w,
                       const float* __restrict__ qb, const float* __restrict__ kb,
                       const float* __restrict__ vb, const float* __restrict__ bt,
                       const float* __restrict__ te,
                       const float* __restrict__ a1w, const float* __restrict__ a1b,
                       const float* __restrict__ a2w, const float* __restrict__ a2b,
                       unsigned short* __restrict__ qkvT, unsigned short* __restrict__ oT,
                       unsigned short* __restrict__ f1T, unsigned short* __restrict__ f2T,
                       float* __restrict__ qkvB, float* __restrict__ bias_full,
                       float* __restrict__ ss1, float* __restrict__ ss2) {
    int t = blockIdx.x * 256 + threadIdx.x;
    if (t < 196608) {                       // qkvT [768][256]
        int n = t >> 8, k = t & 255;
        const float* w = n < 256 ? qw : (n < 512 ? kw : vw);
        qkvT[t] = f2b(w[k * 256 + (n & 255)]);
    } else if (t < 262144) {                // oT [256][256]
        int i = t - 196608; int n = i >> 8, k = i & 255;
        oT[i] = f2b(ow[k * 256 + n]);
    } else if (t < 524288) {                // f1T [1024][256]
        int i = t - 262144; int n = i >> 8, k = i & 255;
        f1T[i] = f2b(f1w[k * 1024 + n]);
    } else if (t < 786432) {                // f2T [256][1024]
        int i = t - 524288; int n = i >> 10, k = i & 1023;
        f2T[i] = f2b(f2w[k * 256 + n]);
    } else if (t < 787200) {                // qkv bias [768]
        int i = t - 786432;
        qkvB[i] = i < 256 ? qb[i] : (i < 512 ? kb[i - 256] : vb[i - 512]);
    } else if (t < 819968) {                // bias_full [8][64][64]
        int i = t - 787200;
        int head = i >> 12, qk = i & 4095;
        int q = qk >> 6, k = qk & 63;
        int qh = q >> 3, qw2 = q & 7, kh = k >> 3, kw2 = k & 7;
        bias_full[i] = bt[((qh - kh + 7) * 15 + (qw2 - kw2 + 7)) * 8 + head];
    } else if (t < 828160) {                // adaln: 2 x [8][512]
        int i = t - 819968;
        int which = i >> 12;
        int rem = i & 4095;
        int b = rem >> 9, col = rem & 511;
        const float* w = which ? a2w : a1w;
        const float* bb = which ? a2b : a1b;
        const float* tr = te + b * C_;
        float acc = bb[col];
        for (int k = 0; k < C_; ++k) acc += tr[k] * w[k * 512 + col];
        (which ? ss2 : ss1)[b * 512 + col] = acc;
    }
}

// ------ LN + modulate + shift + window partition: one wave per token ---------
__global__ __launch_bounds__(256) void ln_win_k(const float* __restrict__ x,
                                                const float* __restrict__ ss,
                                                unsigned short* __restrict__ xw) {
    int t = blockIdx.x * 4 + (threadIdx.x >> 6);     // token 0..32767
    int lane = threadIdx.x & 63;
    int b = t >> 12, rem = t & 4095;
    int hg = rem >> 6, wg = rem & 63;
    int hs = (hg + SH_) & 63, wsrc = (wg + SH_) & 63;
    size_t src = ((size_t)b << 12) + (hs << 6) + wsrc;
    float4 v = *(const float4*)&x[src * C_ + lane * 4];
    float s = v.x + v.y + v.z + v.w;
    float s2 = v.x * v.x + v.y * v.y + v.z * v.z + v.w * v.w;
#pragma unroll
    for (int m = 1; m < 64; m <<= 1) { s += __shfl_xor(s, m); s2 += __shfl_xor(s2, m); }
    float mu = s * (1.f / 256.f);
    float rstd = rsqrtf(s2 * (1.f / 256.f) - mu * mu + LN_EPS);
    float4 sc = *(const float4*)&ss[b * 512 + lane * 4];
    float4 sh = *(const float4*)&ss[b * 512 + 256 + lane * 4];
    int win = (b << 6) + ((hg >> 3) << 3) + (wg >> 3);
    int pos = ((hg & 7) << 3) + (wg & 7);
    ushort4 pk;
    pk.x = f2b((v.x - mu) * rstd * (1.f + sc.x) + sh.x);
    pk.y = f2b((v.y - mu) * rstd * (1.f + sc.y) + sh.y);
    pk.z = f2b((v.z - mu) * rstd * (1.f + sc.z) + sh.z);
    pk.w = f2b((v.w - mu) * rstd * (1.f + sc.w) + sh.w);
    *(ushort4*)(xw + (size_t)(win * 64 + pos) * C_ + lane * 4) = pk;
}

// --------------- bf16 MFMA GEMM, 128x128 tile, BK=128 (R12), swizzled LDS ----
// R0 template with BK doubled 64->128: same staging pattern (h-loop 2->4),
// LDS 32->64 KB (still exactly 2 blocks/CU), HALF the stage+drain barriers
// (K=256: 4->2 k-steps; K=1024: 16->8).
// MODE 0: QKV -> permuted bf16 + bias; MODE 2: FFN1 -> gelu bf16;
// MODE 3: FFN2 -> fp32 residual.
template <int KDIM, int MODE, int NT, int MINW>
__global__ __launch_bounds__(256, MINW) void gemm_bf16_k(
    const unsigned short* __restrict__ A, const unsigned short* __restrict__ Bt,
    const float* __restrict__ bias, const float* __restrict__ res,
    void* __restrict__ Cout, int Nout) {
    __shared__ __align__(16) unsigned short As[4][128 * 32];
    __shared__ __align__(16) unsigned short Bs[4][128 * 32];
    const int blk = blockIdx.x;
    const int xcd = blk & 7;
    const int idx = blk >> 3;
    const int mt = xcd + ((idx / NT) << 3);
    const int nt = idx % NT;
    const int bm = mt * 128, bn = nt * 128;
    const int tid = threadIdx.x;
    const int w = tid >> 6, lane = tid & 63;
    const int quad = lane >> 4, l16 = lane & 15;
    const int wm = (w >> 1) * 64, wn = (w & 1) * 64;
    const int srow = lane >> 2;
    const int qlog = ((lane & 3) ^ ((lane >> 3) & 3)) << 3;
    const int rsw = ((l16 >> 1) & 3) << 3;

    f32x4 acc[4][4] = {};

    for (int k0 = 0; k0 < KDIM; k0 += 128) {
        if (k0) __syncthreads();
#pragma unroll
        for (int h = 0; h < 4; ++h) {
#pragma unroll
            for (int j = 0; j < 2; ++j) {
                int r = j * 64 + w * 16 + srow;
                const unsigned short* ga = A + (size_t)(bm + r) * KDIM + k0 + h * 32 + qlog;
                unsigned short* la = &As[h][j * 2048 + w * 512 + lane * 8];
                __builtin_amdgcn_global_load_lds(
                    (const __attribute__((address_space(1))) void*)ga,
                    (__attribute__((address_space(3))) void*)la, 16, 0, 0);
                const unsigned short* gb = Bt + (size_t)(bn + r) * KDIM + k0 + h * 32 + qlog;
                unsigned short* lb = &Bs[h][j * 2048 + w * 512 + lane * 8];
                __builtin_amdgcn_global_load_lds(
                    (const __attribute__((address_space(1))) void*)gb,
                    (__attribute__((address_space(3))) void*)lb, 16, 0, 0);
            }
        }
        __syncthreads();
#pragma unroll
        for (int h = 0; h < 4; ++h) {
            bf16x8 af[4], bfr[4];
#pragma unroll
            for (int i = 0; i < 4; ++i)
                af[i] = *(const bf16x8*)&As[h][(wm + i * 16 + l16) * 32 + ((quad << 3) ^ rsw)];
#pragma unroll
            for (int j = 0; j < 4; ++j)
                bfr[j] = *(const bf16x8*)&Bs[h][(wn + j * 16 + l16) * 32 + ((quad << 3) ^ rsw)];
#pragma unroll
            for (int i = 0; i < 4; ++i)
#pragma unroll
                for (int j = 0; j < 4; ++j)
                    acc[i][j] = __builtin_amdgcn_mfma_f32_16x16x32_bf16(
                        bfr[j], af[i], acc[i][j], 0, 0, 0);
        }
    }

#pragma unroll
    for (int i = 0; i < 4; ++i) {
        const int row = bm + wm + i * 16 + l16;
        size_t rowbase = 0;
        if (MODE == 0) {
            int win = row >> 6, pos = row & 63;
            rowbase = (size_t)win * 16384 + pos * 32;
        } else {
            rowbase = (size_t)row * Nout;
        }
#pragma unroll
        for (int j = 0; j < 4; ++j) {
            const int col = bn + wn + j * 16 + quad * 4;
            float4 bv = *(const float4*)&bias[col];
            float v0 = acc[i][j][0] + bv.x, v1 = acc[i][j][1] + bv.y;
            float v2 = acc[i][j][2] + bv.z, v3 = acc[i][j][3] + bv.w;
            if (MODE == 0) {
                int which = col >> 8, head = (col >> 5) & 7, dc = col & 31;
                ushort4 pk = {f2b(v0), f2b(v1), f2b(v2), f2b(v3)};
                *(ushort4*)((unsigned short*)Cout + (size_t)which * SL_ + rowbase +
                            head * 2048 + dc) = pk;
            } else if (MODE == 2) {
                ushort4 pk = {f2b(gelu_f(v0)), f2b(gelu_f(v1)),
                              f2b(gelu_f(v2)), f2b(gelu_f(v3))};
                *(ushort4*)((unsigned short*)Cout + rowbase + col) = pk;
            } else {
                float4 rv = *(const float4*)&res[rowbase + col];
                float4 ov = {v0 + rv.x, v1 + rv.y, v2 + rv.z, v3 + rv.w};
                *(float4*)&((float*)Cout)[rowbase + col] = ov;
            }
        }
    }
}

// ------ O-proj GEMM (BM=128, BN=256, BK=128) + window-reverse + residual -----
// ------ + FUSED LayerNorm2 + modulate (R12): writes x1 fp32 and xn2 bf16 -----
// 512 thr, 8 waves = 2(M)x4(N), per-wave 64x64. LN epilogue lifted from R3's
// correctness-verified MODE 1: per-wave partial row sums -> shfl over quads ->
// cross-wave LDS reduction -> normalize + modulate -> xn2. Kills ln_k.
__global__ __launch_bounds__(512, 2) void oproj_ln_k(
    const unsigned short* __restrict__ A, const unsigned short* __restrict__ Bt,
    const float* __restrict__ bias, const float* __restrict__ res,
    float* __restrict__ x1, const float* __restrict__ ss2,
    unsigned short* __restrict__ xn2) {
    __shared__ __align__(16) unsigned short As[4][128 * 32];   // 32 KB
    __shared__ __align__(16) unsigned short Bs[4][256 * 32];   // 64 KB
    const int bm = blockIdx.x * 128;
    const int tid = threadIdx.x;
    const int w = tid >> 6, lane = tid & 63;
    const int quad = lane >> 4, l16 = lane & 15;
    const int wrow = (w >> 2) * 64, wcol = (w & 3) * 64;
    const int rsw = ((l16 >> 1) & 3) << 3;
    const int srow = tid >> 2;                    // 0..127
    const int gch = ((tid & 3) ^ ((srow >> 1) & 3)) << 3;

    f32x4 acc[4][4] = {};

    for (int k0 = 0; k0 < 256; k0 += 128) {
        if (k0) __syncthreads();
#pragma unroll
        for (int h = 0; h < 4; ++h) {
            const unsigned short* ga = A + (size_t)(bm + srow) * 256 + k0 + h * 32 + gch;
            __builtin_amdgcn_global_load_lds(
                (const __attribute__((address_space(1))) void*)ga,
                (__attribute__((address_space(3))) void*)&As[h][tid * 8], 16, 0, 0);
#pragma unroll
            for (int s = 0; s < 2; ++s) {
                const unsigned short* gb = Bt + (size_t)(s * 128 + srow) * 256 + k0 + h * 32 + gch;
                __builtin_amdgcn_global_load_lds(
                    (const __attribute__((address_space(1))) void*)gb,
                    (__attribute__((address_space(3))) void*)&Bs[h][s * 4096 + tid * 8], 16, 0, 0);
            }
        }
        __syncthreads();
#pragma unroll
        for (int h = 0; h < 4; ++h) {
            bf16x8 af[4], bfr[4];
#pragma unroll
            for (int i = 0; i < 4; ++i)
                af[i] = *(const bf16x8*)&As[h][(wrow + i * 16 + l16) * 32 + ((quad << 3) ^ rsw)];
#pragma unroll
            for (int j = 0; j < 4; ++j)
                bfr[j] = *(const bf16x8*)&Bs[h][(wcol + j * 16 + l16) * 32 + ((quad << 3) ^ rsw)];
#pragma unroll
            for (int i = 0; i < 4; ++i)
#pragma unroll
                for (int j = 0; j < 4; ++j)
                    acc[i][j] = __builtin_amdgcn_mfma_f32_16x16x32_bf16(
                        bfr[j], af[i], acc[i][j], 0, 0, 0);
        }
    }

    // -------- epilogue: residual + x1 store + fused LN2 + modulate ----------
    float ps[4], ps2[4];
#pragma unroll
    for (int i = 0; i < 4; ++i) {
        const int row = bm + wrow + i * 16 + l16;
        int win = row >> 6, pos = row & 63;
        int b = win >> 6, wh = (win >> 3) & 7, ww = win & 7;
        int hg = (wh << 3) + (pos >> 3), wg = (ww << 3) + (pos & 7);
        int hd = (hg + SH_) & 63, wd = (wg + SH_) & 63;
        size_t rowbase = (((size_t)b << 12) + (hd << 6) + wd) * C_;
        float s = 0.f, s2 = 0.f;
#pragma unroll
        for (int j = 0; j < 4; ++j) {
            const int col = wcol + j * 16 + quad * 4;
            float4 bv = *(const float4*)&bias[col];
            float4 rv = *(const float4*)&res[rowbase + col];
            float4 ov = {acc[i][j][0] + bv.x + rv.x, acc[i][j][1] + bv.y + rv.y,
                         acc[i][j][2] + bv.z + rv.z, acc[i][j][3] + bv.w + rv.w};
            *(float4*)&x1[rowbase + col] = ov;
            acc[i][j][0] = ov.x; acc[i][j][1] = ov.y;
            acc[i][j][2] = ov.z; acc[i][j][3] = ov.w;
            s += ov.x + ov.y + ov.z + ov.w;
            s2 += ov.x * ov.x + ov.y * ov.y + ov.z * ov.z + ov.w * ov.w;
        }
        ps[i] = s; ps2[i] = s2;
    }
#pragma unroll
    for (int i = 0; i < 4; ++i) {
        ps[i] += __shfl_xor(ps[i], 16);  ps[i] += __shfl_xor(ps[i], 32);
        ps2[i] += __shfl_xor(ps2[i], 16); ps2[i] += __shfl_xor(ps2[i], 32);
    }
    float* sred = (float*)&As[0][0];     // [8 waves][64 rows][2] = 4 KB
    __syncthreads();                      // last compute's ds_reads done
    if (quad == 0) {
#pragma unroll
        for (int i = 0; i < 4; ++i) {
            int r = i * 16 + l16;
            sred[(w * 64 + r) * 2 + 0] = ps[i];
            sred[(w * 64 + r) * 2 + 1] = ps2[i];
        }
    }
    __syncthreads();
#pragma unroll
    for (int i = 0; i < 4; ++i) {
        int r = i * 16 + l16;
        float s = 0.f, s2 = 0.f;
#pragma unroll
        for (int cw = 0; cw < 4; ++cw) {
            s  += sred[(((w >> 2) * 4 + cw) * 64 + r) * 2 + 0];
            s2 += sred[(((w >> 2) * 4 + cw) * 64 + r) * 2 + 1];
        }
        float mu = s * (1.f / 256.f);
        float rstd = rsqrtf(s2 * (1.f / 256.f) - mu * mu + LN_EPS);
        const int row = bm + wrow + i * 16 + l16;
        int win = row >> 6, pos = row & 63;
        int b = win >> 6, wh = (win >> 3) & 7, ww = win & 7;
        int hg = (wh << 3) + (pos >> 3), wg = (ww << 3) + (pos & 7);
        int hd = (hg + SH_) & 63, wd = (wg + SH_) & 63;
        size_t rowbase = (((size_t)b << 12) + (hd << 6) + wd) * C_;
#pragma unroll
        for (int j = 0; j < 4; ++j) {
            const int col = wcol + j * 16 + quad * 4;
            float4 scv = *(const float4*)&ss2[b * 512 + col];
            float4 shv = *(const float4*)&ss2[b * 512 + 256 + col];
            ushort4 pk;
            pk.x = f2b((acc[i][j][0] - mu) * rstd * (1.f + scv.x) + shv.x);
            pk.y = f2b((acc[i][j][1] - mu) * rstd * (1.f + scv.y) + shv.y);
            pk.z = f2b((acc[i][j][2] - mu) * rstd * (1.f + scv.z) + shv.z);
            pk.w = f2b((acc[i][j][3] - mu) * rstd * (1.f + scv.w) + shv.w);
            *(ushort4*)(xn2 + rowbase + col) = pk;
        }
    }
}

// ------------- MFMA window attention: one wave per (window, head) ------------
__global__ __launch_bounds__(256) void attn_mfma_k(
    const unsigned short* __restrict__ qkv, const float* __restrict__ bias_full,
    unsigned short* __restrict__ attn_out) {
    __shared__ __align__(16) unsigned short Pb[4][64 * 66];
    __shared__ __align__(16) unsigned short Vt[4][32 * 66];
    const int w = threadIdx.x >> 6, lane = threadIdx.x & 63;
    const int wh = blockIdx.x * 4 + w;        // 0..4095
    const int win = wh >> 3, head = wh & 7;
    const int quad = lane >> 4, l16 = lane & 15;

    const unsigned short* qp = qkv + (size_t)win * 16384 + head * 2048;
    const unsigned short* kp = qp + SL_;
    const unsigned short* vp = qp + 2 * (size_t)SL_;

    // stage V transposed: Vt[d][pos]
    {
        const uint4* v4 = (const uint4*)(vp + lane * 32);
        unsigned short* dst = &Vt[w][0];
#pragma unroll
        for (int c = 0; c < 4; ++c) {
            uint4 u = v4[c];
            unsigned int uu[4] = {u.x, u.y, u.z, u.w};
#pragma unroll
            for (int p = 0; p < 4; ++p) {
                int d0 = c * 8 + p * 2;
                dst[d0 * 66 + lane] = (unsigned short)(uu[p] & 0xffff);
                dst[(d0 + 1) * 66 + lane] = (unsigned short)(uu[p] >> 16);
            }
        }
    }

    bf16x8 qf[4], kf[4];
#pragma unroll
    for (int i = 0; i < 4; ++i) {
        qf[i] = *(const bf16x8*)(qp + (i * 16 + l16) * 32 + quad * 8);
        kf[i] = *(const bf16x8*)(kp + (i * 16 + l16) * 32 + quad * 8);
    }

    f32x4 s[4][4] = {};
#pragma unroll
    for (int i = 0; i < 4; ++i)
#pragma unroll
        for (int j = 0; j < 4; ++j)
            s[i][j] = __builtin_amdgcn_mfma_f32_16x16x32_bf16(qf[i], kf[j], s[i][j], 0, 0, 0);

    const float scale = 0.17677669529663687f;
    const float* bf = bias_full + head * 4096;
    float rs[4][4];
#pragma unroll
    for (int i = 0; i < 4; ++i) {
#pragma unroll
        for (int r = 0; r < 4; ++r) {
            int row = i * 16 + quad * 4 + r;
            float acc = 0.f;
#pragma unroll
            for (int j = 0; j < 4; ++j) {
                float e = __expf(s[i][j][r] * scale + bf[row * 64 + j * 16 + l16]);
                s[i][j][r] = e;
                acc += e;
            }
#pragma unroll
            for (int msk = 1; msk < 16; msk <<= 1) acc += __shfl_xor(acc, msk);
            rs[i][r] = 1.f / acc;
        }
    }

#pragma unroll
    for (int i = 0; i < 4; ++i)
#pragma unroll
        for (int j = 0; j < 4; ++j)
#pragma unroll
            for (int r = 0; r < 4; ++r)
                Pb[w][(i * 16 + quad * 4 + r) * 66 + j * 16 + l16] = f2b(s[i][j][r]);

    __syncthreads();

    f32x4 o[4][2] = {};
#pragma unroll
    for (int st = 0; st < 2; ++st) {
        bf16x8 bv[2];
#pragma unroll
        for (int jo = 0; jo < 2; ++jo)
            bv[jo] = *(const bf16x8*)&Vt[w][(jo * 16 + l16) * 66 + st * 32 + quad * 8];
#pragma unroll
        for (int i = 0; i < 4; ++i) {
            bf16x8 af = *(const bf16x8*)&Pb[w][(i * 16 + l16) * 66 + st * 32 + quad * 8];
#pragma unroll
            for (int jo = 0; jo < 2; ++jo)
                o[i][jo] = __builtin_amdgcn_mfma_f32_16x16x32_bf16(af, bv[jo], o[i][jo], 0, 0, 0);
        }
    }

#pragma unroll
    for (int i = 0; i < 4; ++i)
#pragma unroll
        for (int jo = 0; jo < 2; ++jo)
#pragma unroll
            for (int r = 0; r < 4; ++r) {
                int row = i * 16 + quad * 4 + r;
                int d = jo * 16 + l16;
                attn_out[((size_t)(win * 64 + row)) * C_ + head * 32 + d] =
                    f2b(o[i][jo][r] * rs[i][r]);
            }
}

extern "C" void kernel_launch(void* const* d_in, const int* in_sizes, int n_in,
                              void* d_out, int out_size, void* d_ws, size_t ws_size,
                              hipStream_t stream) {
    const float* x        = (const float*)d_in[0];
    const float* t_embed  = (const float*)d_in[1];
    const float* adaln1_w = (const float*)d_in[4];
    const float* adaln1_b = (const float*)d_in[5];
    const float* adaln2_w = (const float*)d_in[6];
    const float* adaln2_b = (const float*)d_in[7];
    const float* bt       = (const float*)d_in[8];
    const float* q_w = (const float*)d_in[9],  *q_b = (const float*)d_in[10];
    const float* k_w = (const float*)d_in[11], *k_b = (const float*)d_in[12];
    const float* v_w = (const float*)d_in[13], *v_b = (const float*)d_in[14];
    const float* o_w = (const float*)d_in[15], *o_b = (const float*)d_in[16];
    const float* f1_w = (const float*)d_in[17], *f1_b = (const float*)d_in[18];
    const float* f2_w = (const float*)d_in[19], *f2_b = (const float*)d_in[20];
    float* out = (float*)d_out;

    char* wsb = (char*)d_ws;
    float* ss1            = (float*)(wsb + 0);
    float* ss2            = (float*)(wsb + 16384);
    float* qkvB           = (float*)(wsb + 32768);
    unsigned short* qkvT  = (unsigned short*)(wsb + 36864);
    unsigned short* oT    = (unsigned short*)(wsb + 430080);
    unsigned short* f1T   = (unsigned short*)(wsb + 561152);
    unsigned short* f2T   = (unsigned short*)(wsb + 1085440);
    float* bias_full      = (float*)(wsb + 1609728);               // 131072 B
    unsigned short* xw    = (unsigned short*)(wsb + 2097152);      // [M][256] bf16
    unsigned short* qkv   = (unsigned short*)(wsb + 18874368);     // 3 x SL_ bf16
    unsigned short* attn  = (unsigned short*)(wsb + 69206016);     // [M][256] bf16
    unsigned short* xn2   = xw;                                    // reuse
    unsigned short* hbuf  = qkv;                                   // reuse (67.1 MB)
    float* x1             = (float*)(wsb + 85983232);              // [M][256] fp32

    prep_k<<<3235, 256, 0, stream>>>(q_w, k_w, v_w, o_w, f1_w, f2_w, q_b, k_b, v_b, bt,
                                     t_embed, adaln1_w, adaln1_b, adaln2_w, adaln2_b,
                                     qkvT, oT, f1T, f2T, qkvB, bias_full, ss1, ss2);
    ln_win_k<<<8192, 256, 0, stream>>>(x, ss1, xw);

    gemm_bf16_k<256, 0, 6, 2><<<1536, 256, 0, stream>>>(xw, qkvT, qkvB, nullptr, qkv, 768);

    attn_mfma_k<<<1024, 256, 0, stream>>>(qkv, bias_full, attn);

    // O-proj + residual + fused LN2/modulate: 256 blocks (1/CU), replaces ln_k
    oproj_ln_k<<<256, 512, 0, stream>>>(attn, oT, o_b, x, x1, ss2, xn2);

    gemm_bf16_k<256, 2, 8, 2><<<2048, 256, 0, stream>>>(xn2, f1T, f1_b, nullptr, hbuf, 1024);
    gemm_bf16_k<1024, 3, 2, 2><<<512, 256, 0, stream>>>(hbuf, f2T, f2_b, x1, out, 256);
}

// Round 6
// 261.880 us; speedup vs baseline: 1.2121x; 1.0341x over previous
//
#include <hip/hip_runtime.h>
#include <math.h>

#define WS_ 8
#define NH_ 8
#define C_ 256
#define B_ 8
#define M_ 32768            // B_*L_
#define SH_ 4               // WS_/2
#define LN_EPS 1e-5f
#define SL_ 8388608         // elements per [M,C] slot

typedef __attribute__((ext_vector_type(8))) short bf16x8;
typedef __attribute__((ext_vector_type(4))) float f32x4;

__device__ inline float b2f(unsigned short u) {
    union { unsigned int i; float f; } c; c.i = ((unsigned int)u) << 16; return c.f;
}
__device__ inline unsigned short f2b(float f) {
    union { unsigned int i; float f; } c; c.f = f;
    unsigned int u = c.i;
    return (unsigned short)((u + 0x7FFFu + ((u >> 16) & 1u)) >> 16);
}
__device__ inline float gelu_f(float x) {
    // tanh-form GELU: x * sigmoid(1.59576912*(x + 0.044715 x^3)); |err| < ~1e-3
    float t = 1.59576912160573f * (x + 0.044715f * x * x * x);
    return x / (1.f + __expf(-t));
}

// ---------- weight prep + adaln fused: bf16 [N][K] transposes, qkv bias,
// ---------- bias_full, and ss = t_embed @ w + b for both adaln layers -------
__global__ void prep_k(const float* __restrict__ qw, const float* __restrict__ kw,
                       const float* __restrict__ vw, const float* __restrict__ ow,
                       const float* __restrict__ f1w, const float* __restrict__ f2w,
                       const float* __restrict__ qb, const float* __restrict__ kb,
                       const float* __restrict__ vb, const float* __restrict__ bt,
                       const float* __restrict__ te,
                       const float* __restrict__ a1w, const float* __restrict__ a1b,
                       const float* __restrict__ a2w, const float* __restrict__ a2b,
                       unsigned short* __restrict__ qkvT, unsigned short* __restrict__ oT,
                       unsigned short* __restrict__ f1T, unsigned short* __restrict__ f2T,
                       float* __restrict__ qkvB, float* __restrict__ bias_full,
                       float* __restrict__ ss1, float* __restrict__ ss2) {
    int t = blockIdx.x * 256 + threadIdx.x;
    if (t < 196608) {                       // qkvT [768][256]
        int n = t >> 8, k = t & 255;
        const float* w = n < 256 ? qw : (n < 512 ? kw : vw);
        qkvT[t] = f2b(w[k * 256 + (n & 255)]);
    } else if (t < 262144) {                // oT [256][256]
        int i = t - 196608; int n = i >> 8, k = i & 255;
        oT[i] = f2b(ow[k * 256 + n]);
    } else if (t < 524288) {                // f1T [1024][256]
        int i = t - 262144; int n = i >> 8, k = i & 255;
        f1T[i] = f2b(f1w[k * 1024 + n]);
    } else if (t < 786432) {                // f2T [256][1024]
        int i = t - 524288; int n = i >> 10, k = i & 1023;
        f2T[i] = f2b(f2w[k * 256 + n]);
    } else if (t < 787200) {                // qkv bias [768]
        int i = t - 786432;
        qkvB[i] = i < 256 ? qb[i] : (i < 512 ? kb[i - 256] : vb[i - 512]);
    } else if (t < 819968) {                // bias_full [8][64][64]
        int i = t - 787200;
        int head = i >> 12, qk = i & 4095;
        int q = qk >> 6, k = qk & 63;
        int qh = q >> 3, qw2 = q & 7, kh = k >> 3, kw2 = k & 7;
        bias_full[i] = bt[((qh - kh + 7) * 15 + (qw2 - kw2 + 7)) * 8 + head];
    } else if (t < 828160) {                // adaln: 2 x [8][512]
        int i = t - 819968;
        int which = i >> 12;
        int rem = i & 4095;
        int b = rem >> 9, col = rem & 511;
        const float* w = which ? a2w : a1w;
        const float* bb = which ? a2b : a1b;
        const float* tr = te + b * C_;
        float acc = bb[col];
        for (int k = 0; k < C_; ++k) acc += tr[k] * w[k * 512 + col];
        (which ? ss2 : ss1)[b * 512 + col] = acc;
    }
}

// ------ LN + modulate + shift + window partition: one wave per token ---------
__global__ __launch_bounds__(256) void ln_win_k(const float* __restrict__ x,
                                                const float* __restrict__ ss,
                                                unsigned short* __restrict__ xw) {
    int t = blockIdx.x * 4 + (threadIdx.x >> 6);     // token 0..32767
    int lane = threadIdx.x & 63;
    int b = t >> 12, rem = t & 4095;
    int hg = rem >> 6, wg = rem & 63;
    int hs = (hg + SH_) & 63, wsrc = (wg + SH_) & 63;
    size_t src = ((size_t)b << 12) + (hs << 6) + wsrc;
    float4 v = *(const float4*)&x[src * C_ + lane * 4];
    float s = v.x + v.y + v.z + v.w;
    float s2 = v.x * v.x + v.y * v.y + v.z * v.z + v.w * v.w;
#pragma unroll
    for (int m = 1; m < 64; m <<= 1) { s += __shfl_xor(s, m); s2 += __shfl_xor(s2, m); }
    float mu = s * (1.f / 256.f);
    float rstd = rsqrtf(s2 * (1.f / 256.f) - mu * mu + LN_EPS);
    float4 sc = *(const float4*)&ss[b * 512 + lane * 4];
    float4 sh = *(const float4*)&ss[b * 512 + 256 + lane * 4];
    int win = (b << 6) + ((hg >> 3) << 3) + (wg >> 3);
    int pos = ((hg & 7) << 3) + (wg & 7);
    ushort4 pk;
    pk.x = f2b((v.x - mu) * rstd * (1.f + sc.x) + sh.x);
    pk.y = f2b((v.y - mu) * rstd * (1.f + sc.y) + sh.y);
    pk.z = f2b((v.z - mu) * rstd * (1.f + sc.z) + sh.z);
    pk.w = f2b((v.w - mu) * rstd * (1.f + sc.w) + sh.w);
    *(ushort4*)(xw + (size_t)(win * 64 + pos) * C_ + lane * 4) = pk;
}

// --------------- bf16 MFMA GEMM, 128x128 tile, BK=64 (R0-exact K-loop) -------
// R6: epilogue LDS-bounce for bf16 outputs (MODE 0/2): pack acc->bf16 into the
// freed 32KB LDS (XOR swizzle chunk^(row&7), <=2-way conflicts both sides),
// barrier, store 16B/lane with 16 lanes = 256B contiguous runs. Replaces the
// scattered 8B stores (16 cache lines per wave-store -> 1-4).
// MODE 0: QKV -> permuted bf16 + bias; MODE 2: FFN1 -> gelu bf16;
// MODE 3: FFN2 -> fp32 residual (direct stores, 64B chunks - kept).
template <int KDIM, int MODE, int NT, int MINW>
__global__ __launch_bounds__(256, MINW) void gemm_bf16_k(
    const unsigned short* __restrict__ A, const unsigned short* __restrict__ Bt,
    const float* __restrict__ bias, const float* __restrict__ res,
    void* __restrict__ Cout, int Nout) {
    __shared__ __align__(16) unsigned short smem[16384];   // 32 KB
    unsigned short (*As)[4096] = (unsigned short (*)[4096])&smem[0];
    unsigned short (*Bs)[4096] = (unsigned short (*)[4096])&smem[8192];
    const int blk = blockIdx.x;
    const int xcd = blk & 7;
    const int idx = blk >> 3;
    const int mt = xcd + ((idx / NT) << 3);
    const int nt = idx % NT;
    const int bm = mt * 128, bn = nt * 128;
    const int tid = threadIdx.x;
    const int w = tid >> 6, lane = tid & 63;
    const int quad = lane >> 4, l16 = lane & 15;
    const int wm = (w >> 1) * 64, wn = (w & 1) * 64;
    const int srow = lane >> 2;
    const int qlog = ((lane & 3) ^ ((lane >> 3) & 3)) << 3;
    const int rsw = ((l16 >> 1) & 3) << 3;

    f32x4 acc[4][4] = {};

    for (int k0 = 0; k0 < KDIM; k0 += 64) {
        if (k0) __syncthreads();
#pragma unroll
        for (int h = 0; h < 2; ++h) {
#pragma unroll
            for (int j = 0; j < 2; ++j) {
                int r = j * 64 + w * 16 + srow;
                const unsigned short* ga = A + (size_t)(bm + r) * KDIM + k0 + h * 32 + qlog;
                unsigned short* la = &As[h][j * 2048 + w * 512 + lane * 8];
                __builtin_amdgcn_global_load_lds(
                    (const __attribute__((address_space(1))) void*)ga,
                    (__attribute__((address_space(3))) void*)la, 16, 0, 0);
                const unsigned short* gb = Bt + (size_t)(bn + r) * KDIM + k0 + h * 32 + qlog;
                unsigned short* lb = &Bs[h][j * 2048 + w * 512 + lane * 8];
                __builtin_amdgcn_global_load_lds(
                    (const __attribute__((address_space(1))) void*)gb,
                    (__attribute__((address_space(3))) void*)lb, 16, 0, 0);
            }
        }
        __syncthreads();
#pragma unroll
        for (int h = 0; h < 2; ++h) {
            bf16x8 af[4], bfr[4];
#pragma unroll
            for (int i = 0; i < 4; ++i)
                af[i] = *(const bf16x8*)&As[h][(wm + i * 16 + l16) * 32 + ((quad << 3) ^ rsw)];
#pragma unroll
            for (int j = 0; j < 4; ++j)
                bfr[j] = *(const bf16x8*)&Bs[h][(wn + j * 16 + l16) * 32 + ((quad << 3) ^ rsw)];
#pragma unroll
            for (int i = 0; i < 4; ++i)
#pragma unroll
                for (int j = 0; j < 4; ++j)
                    acc[i][j] = __builtin_amdgcn_mfma_f32_16x16x32_bf16(
                        bfr[j], af[i], acc[i][j], 0, 0, 0);
        }
    }

    if constexpr (MODE == 0 || MODE == 2) {
        // ---- LDS-bounce coalesced epilogue (R6) ----
        __syncthreads();   // all frag ds_reads done before overwriting smem
#pragma unroll
        for (int i = 0; i < 4; ++i) {
            const int lrow = wm + i * 16 + l16;
#pragma unroll
            for (int j = 0; j < 4; ++j) {
                const int lcol = wn + j * 16 + quad * 4;
                float4 bv = *(const float4*)&bias[bn + lcol];
                float v0 = acc[i][j][0] + bv.x, v1 = acc[i][j][1] + bv.y;
                float v2 = acc[i][j][2] + bv.z, v3 = acc[i][j][3] + bv.w;
                ushort4 pk;
                if (MODE == 2) {
                    pk.x = f2b(gelu_f(v0)); pk.y = f2b(gelu_f(v1));
                    pk.z = f2b(gelu_f(v2)); pk.w = f2b(gelu_f(v3));
                } else {
                    pk.x = f2b(v0); pk.y = f2b(v1); pk.z = f2b(v2); pk.w = f2b(v3);
                }
                int sw = (lcol >> 3) ^ (lrow & 7);
                *(ushort4*)&smem[lrow * 128 + sw * 8 + (lcol & 7)] = pk;
            }
        }
        __syncthreads();
#pragma unroll
        for (int p = 0; p < 8; ++p) {
            const int lrow = p * 16 + (tid >> 4);
            const int c16 = tid & 15;
            bf16x8 v = *(const bf16x8*)&smem[lrow * 128 + ((c16 ^ (lrow & 7)) * 8)];
            const int grow = bm + lrow;
            if (MODE == 2) {
                *(bf16x8*)((unsigned short*)Cout + (size_t)grow * Nout + bn + c16 * 8) = v;
            } else {
                int win = grow >> 6, pos = grow & 63;
                int col = bn + c16 * 8;
                int which = col >> 8, head = (col >> 5) & 7, dc = col & 31;
                *(bf16x8*)((unsigned short*)Cout + (size_t)which * SL_ +
                           (size_t)win * 16384 + pos * 32 + head * 2048 + dc) = v;
            }
        }
    } else {
        // ---- direct epilogue (MODE 3: fp32 residual) ----
#pragma unroll
        for (int i = 0; i < 4; ++i) {
            const int row = bm + wm + i * 16 + l16;
            size_t rowbase = (size_t)row * Nout;
#pragma unroll
            for (int j = 0; j < 4; ++j) {
                const int col = bn + wn + j * 16 + quad * 4;
                float4 bv = *(const float4*)&bias[col];
                float v0 = acc[i][j][0] + bv.x, v1 = acc[i][j][1] + bv.y;
                float v2 = acc[i][j][2] + bv.z, v3 = acc[i][j][3] + bv.w;
                float4 rv = *(const float4*)&res[rowbase + col];
                float4 ov = {v0 + rv.x, v1 + rv.y, v2 + rv.z, v3 + rv.w};
                *(float4*)&((float*)Cout)[rowbase + col] = ov;
            }
        }
    }
}

// ------ O-proj GEMM (BM=128, BN=256, BK=128) + window-reverse + residual -----
// ------ + FUSED LayerNorm2 + modulate: writes x1 fp32 and xn2 bf16 -----------
__global__ __launch_bounds__(512, 2) void oproj_ln_k(
    const unsigned short* __restrict__ A, const unsigned short* __restrict__ Bt,
    const float* __restrict__ bias, const float* __restrict__ res,
    float* __restrict__ x1, const float* __restrict__ ss2,
    unsigned short* __restrict__ xn2) {
    __shared__ __align__(16) unsigned short As[4][128 * 32];   // 32 KB
    __shared__ __align__(16) unsigned short Bs[4][256 * 32];   // 64 KB
    const int bm = blockIdx.x * 128;
    const int tid = threadIdx.x;
    const int w = tid >> 6, lane = tid & 63;
    const int quad = lane >> 4, l16 = lane & 15;
    const int wrow = (w >> 2) * 64, wcol = (w & 3) * 64;
    const int rsw = ((l16 >> 1) & 3) << 3;
    const int srow = tid >> 2;                    // 0..127
    const int gch = ((tid & 3) ^ ((srow >> 1) & 3)) << 3;

    f32x4 acc[4][4] = {};

    for (int k0 = 0; k0 < 256; k0 += 128) {
        if (k0) __syncthreads();
#pragma unroll
        for (int h = 0; h < 4; ++h) {
            const unsigned short* ga = A + (size_t)(bm + srow) * 256 + k0 + h * 32 + gch;
            __builtin_amdgcn_global_load_lds(
                (const __attribute__((address_space(1))) void*)ga,
                (__attribute__((address_space(3))) void*)&As[h][tid * 8], 16, 0, 0);
#pragma unroll
            for (int s = 0; s < 2; ++s) {
                const unsigned short* gb = Bt + (size_t)(s * 128 + srow) * 256 + k0 + h * 32 + gch;
                __builtin_amdgcn_global_load_lds(
                    (const __attribute__((address_space(1))) void*)gb,
                    (__attribute__((address_space(3))) void*)&Bs[h][s * 4096 + tid * 8], 16, 0, 0);
            }
        }
        __syncthreads();
#pragma unroll
        for (int h = 0; h < 4; ++h) {
            bf16x8 af[4], bfr[4];
#pragma unroll
            for (int i = 0; i < 4; ++i)
                af[i] = *(const bf16x8*)&As[h][(wrow + i * 16 + l16) * 32 + ((quad << 3) ^ rsw)];
#pragma unroll
            for (int j = 0; j < 4; ++j)
                bfr[j] = *(const bf16x8*)&Bs[h][(wcol + j * 16 + l16) * 32 + ((quad << 3) ^ rsw)];
#pragma unroll
            for (int i = 0; i < 4; ++i)
#pragma unroll
                for (int j = 0; j < 4; ++j)
                    acc[i][j] = __builtin_amdgcn_mfma_f32_16x16x32_bf16(
                        bfr[j], af[i], acc[i][j], 0, 0, 0);
        }
    }

    // -------- epilogue: residual + x1 store + fused LN2 + modulate ----------
    float ps[4], ps2[4];
#pragma unroll
    for (int i = 0; i < 4; ++i) {
        const int row = bm + wrow + i * 16 + l16;
        int win = row >> 6, pos = row & 63;
        int b = win >> 6, wh = (win >> 3) & 7, ww = win & 7;
        int hg = (wh << 3) + (pos >> 3), wg = (ww << 3) + (pos & 7);
        int hd = (hg + SH_) & 63, wd = (wg + SH_) & 63;
        size_t rowbase = (((size_t)b << 12) + (hd << 6) + wd) * C_;
        float s = 0.f, s2 = 0.f;
#pragma unroll
        for (int j = 0; j < 4; ++j) {
            const int col = wcol + j * 16 + quad * 4;
            float4 bv = *(const float4*)&bias[col];
            float4 rv = *(const float4*)&res[rowbase + col];
            float4 ov = {acc[i][j][0] + bv.x + rv.x, acc[i][j][1] + bv.y + rv.y,
                         acc[i][j][2] + bv.z + rv.z, acc[i][j][3] + bv.w + rv.w};
            *(float4*)&x1[rowbase + col] = ov;
            acc[i][j][0] = ov.x; acc[i][j][1] = ov.y;
            acc[i][j][2] = ov.z; acc[i][j][3] = ov.w;
            s += ov.x + ov.y + ov.z + ov.w;
            s2 += ov.x * ov.x + ov.y * ov.y + ov.z * ov.z + ov.w * ov.w;
        }
        ps[i] = s; ps2[i] = s2;
    }
#pragma unroll
    for (int i = 0; i < 4; ++i) {
        ps[i] += __shfl_xor(ps[i], 16);  ps[i] += __shfl_xor(ps[i], 32);
        ps2[i] += __shfl_xor(ps2[i], 16); ps2[i] += __shfl_xor(ps2[i], 32);
    }
    float* sred = (float*)&As[0][0];     // [8 waves][64 rows][2] = 4 KB
    __syncthreads();                      // last compute's ds_reads done
    if (quad == 0) {
#pragma unroll
        for (int i = 0; i < 4; ++i) {
            int r = i * 16 + l16;
            sred[(w * 64 + r) * 2 + 0] = ps[i];
            sred[(w * 64 + r) * 2 + 1] = ps2[i];
        }
    }
    __syncthreads();
#pragma unroll
    for (int i = 0; i < 4; ++i) {
        int r = i * 16 + l16;
        float s = 0.f, s2 = 0.f;
#pragma unroll
        for (int cw = 0; cw < 4; ++cw) {
            s  += sred[(((w >> 2) * 4 + cw) * 64 + r) * 2 + 0];
            s2 += sred[(((w >> 2) * 4 + cw) * 64 + r) * 2 + 1];
        }
        float mu = s * (1.f / 256.f);
        float rstd = rsqrtf(s2 * (1.f / 256.f) - mu * mu + LN_EPS);
        const int row = bm + wrow + i * 16 + l16;
        int win = row >> 6, pos = row & 63;
        int b = win >> 6, wh = (win >> 3) & 7, ww = win & 7;
        int hg = (wh << 3) + (pos >> 3), wg = (ww << 3) + (pos & 7);
        int hd = (hg + SH_) & 63, wd = (wg + SH_) & 63;
        size_t rowbase = (((size_t)b << 12) + (hd << 6) + wd) * C_;
#pragma unroll
        for (int j = 0; j < 4; ++j) {
            const int col = wcol + j * 16 + quad * 4;
            float4 scv = *(const float4*)&ss2[b * 512 + col];
            float4 shv = *(const float4*)&ss2[b * 512 + 256 + col];
            ushort4 pk;
            pk.x = f2b((acc[i][j][0] - mu) * rstd * (1.f + scv.x) + shv.x);
            pk.y = f2b((acc[i][j][1] - mu) * rstd * (1.f + scv.y) + shv.y);
            pk.z = f2b((acc[i][j][2] - mu) * rstd * (1.f + scv.z) + shv.z);
            pk.w = f2b((acc[i][j][3] - mu) * rstd * (1.f + scv.w) + shv.w);
            *(ushort4*)(xn2 + rowbase + col) = pk;
        }
    }
}

// ------------- MFMA window attention: one wave per (window, head) ------------
__global__ __launch_bounds__(256) void attn_mfma_k(
    const unsigned short* __restrict__ qkv, const float* __restrict__ bias_full,
    unsigned short* __restrict__ attn_out) {
    __shared__ __align__(16) unsigned short Pb[4][64 * 66];
    __shared__ __align__(16) unsigned short Vt[4][32 * 66];
    const int w = threadIdx.x >> 6, lane = threadIdx.x & 63;
    const int wh = blockIdx.x * 4 + w;        // 0..4095
    const int win = wh >> 3, head = wh & 7;
    const int quad = lane >> 4, l16 = lane & 15;

    const unsigned short* qp = qkv + (size_t)win * 16384 + head * 2048;
    const unsigned short* kp = qp + SL_;
    const unsigned short* vp = qp + 2 * (size_t)SL_;

    // stage V transposed: Vt[d][pos]
    {
        const uint4* v4 = (const uint4*)(vp + lane * 32);
        unsigned short* dst = &Vt[w][0];
#pragma unroll
        for (int c = 0; c < 4; ++c) {
            uint4 u = v4[c];
            unsigned int uu[4] = {u.x, u.y, u.z, u.w};
#pragma unroll
            for (int p = 0; p < 4; ++p) {
                int d0 = c * 8 + p * 2;
                dst[d0 * 66 + lane] = (unsigned short)(uu[p] & 0xffff);
                dst[(d0 + 1) * 66 + lane] = (unsigned short)(uu[p] >> 16);
            }
        }
    }

    bf16x8 qf[4], kf[4];
#pragma unroll
    for (int i = 0; i < 4; ++i) {
        qf[i] = *(const bf16x8*)(qp + (i * 16 + l16) * 32 + quad * 8);
        kf[i] = *(const bf16x8*)(kp + (i * 16 + l16) * 32 + quad * 8);
    }

    f32x4 s[4][4] = {};
#pragma unroll
    for (int i = 0; i < 4; ++i)
#pragma unroll
        for (int j = 0; j < 4; ++j)
            s[i][j] = __builtin_amdgcn_mfma_f32_16x16x32_bf16(qf[i], kf[j], s[i][j], 0, 0, 0);

    const float scale = 0.17677669529663687f;
    const float* bf = bias_full + head * 4096;
    float rs[4][4];
#pragma unroll
    for (int i = 0; i < 4; ++i) {
#pragma unroll
        for (int r = 0; r < 4; ++r) {
            int row = i * 16 + quad * 4 + r;
            float acc = 0.f;
#pragma unroll
            for (int j = 0; j < 4; ++j) {
                float e = __expf(s[i][j][r] * scale + bf[row * 64 + j * 16 + l16]);
                s[i][j][r] = e;
                acc += e;
            }
#pragma unroll
            for (int msk = 1; msk < 16; msk <<= 1) acc += __shfl_xor(acc, msk);
            rs[i][r] = 1.f / acc;
        }
    }

#pragma unroll
    for (int i = 0; i < 4; ++i)
#pragma unroll
        for (int j = 0; j < 4; ++j)
#pragma unroll
            for (int r = 0; r < 4; ++r)
                Pb[w][(i * 16 + quad * 4 + r) * 66 + j * 16 + l16] = f2b(s[i][j][r]);

    __syncthreads();

    f32x4 o[4][2] = {};
#pragma unroll
    for (int st = 0; st < 2; ++st) {
        bf16x8 bv[2];
#pragma unroll
        for (int jo = 0; jo < 2; ++jo)
            bv[jo] = *(const bf16x8*)&Vt[w][(jo * 16 + l16) * 66 + st * 32 + quad * 8];
#pragma unroll
        for (int i = 0; i < 4; ++i) {
            bf16x8 af = *(const bf16x8*)&Pb[w][(i * 16 + l16) * 66 + st * 32 + quad * 8];
#pragma unroll
            for (int jo = 0; jo < 2; ++jo)
                o[i][jo] = __builtin_amdgcn_mfma_f32_16x16x32_bf16(af, bv[jo], o[i][jo], 0, 0, 0);
        }
    }

#pragma unroll
    for (int i = 0; i < 4; ++i)
#pragma unroll
        for (int jo = 0; jo < 2; ++jo)
#pragma unroll
            for (int r = 0; r < 4; ++r) {
                int row = i * 16 + quad * 4 + r;
                int d = jo * 16 + l16;
                attn_out[((size_t)(win * 64 + row)) * C_ + head * 32 + d] =
                    f2b(o[i][jo][r] * rs[i][r]);
            }
}

extern "C" void kernel_launch(void* const* d_in, const int* in_sizes, int n_in,
                              void* d_out, int out_size, void* d_ws, size_t ws_size,
                              hipStream_t stream) {
    const float* x        = (const float*)d_in[0];
    const float* t_embed  = (const float*)d_in[1];
    const float* adaln1_w = (const float*)d_in[4];
    const float* adaln1_b = (const float*)d_in[5];
    const float* adaln2_w = (const float*)d_in[6];
    const float* adaln2_b = (const float*)d_in[7];
    const float* bt       = (const float*)d_in[8];
    const float* q_w = (const float*)d_in[9],  *q_b = (const float*)d_in[10];
    const float* k_w = (const float*)d_in[11], *k_b = (const float*)d_in[12];
    const float* v_w = (const float*)d_in[13], *v_b = (const float*)d_in[14];
    const float* o_w = (const float*)d_in[15], *o_b = (const float*)d_in[16];
    const float* f1_w = (const float*)d_in[17], *f1_b = (const float*)d_in[18];
    const float* f2_w = (const float*)d_in[19], *f2_b = (const float*)d_in[20];
    float* out = (float*)d_out;

    char* wsb = (char*)d_ws;
    float* ss1            = (float*)(wsb + 0);
    float* ss2            = (float*)(wsb + 16384);
    float* qkvB           = (float*)(wsb + 32768);
    unsigned short* qkvT  = (unsigned short*)(wsb + 36864);
    unsigned short* oT    = (unsigned short*)(wsb + 430080);
    unsigned short* f1T   = (unsigned short*)(wsb + 561152);
    unsigned short* f2T   = (unsigned short*)(wsb + 1085440);
    float* bias_full      = (float*)(wsb + 1609728);               // 131072 B
    unsigned short* xw    = (unsigned short*)(wsb + 2097152);      // [M][256] bf16
    unsigned short* qkv   = (unsigned short*)(wsb + 18874368);     // 3 x SL_ bf16
    unsigned short* attn  = (unsigned short*)(wsb + 69206016);     // [M][256] bf16
    unsigned short* xn2   = xw;                                    // reuse
    unsigned short* hbuf  = qkv;                                   // reuse (67.1 MB)
    float* x1             = (float*)(wsb + 85983232);              // [M][256] fp32

    prep_k<<<3235, 256, 0, stream>>>(q_w, k_w, v_w, o_w, f1_w, f2_w, q_b, k_b, v_b, bt,
                                     t_embed, adaln1_w, adaln1_b, adaln2_w, adaln2_b,
                                     qkvT, oT, f1T, f2T, qkvB, bias_full, ss1, ss2);
    ln_win_k<<<8192, 256, 0, stream>>>(x, ss1, xw);

    gemm_bf16_k<256, 0, 6, 3><<<1536, 256, 0, stream>>>(xw, qkvT, qkvB, nullptr, qkv, 768);

    attn_mfma_k<<<1024, 256, 0, stream>>>(qkv, bias_full, attn);

    // O-proj + residual + fused LN2/modulate: 256 blocks (1/CU), replaces ln_k
    oproj_ln_k<<<256, 512, 0, stream>>>(attn, oT, o_b, x, x1, ss2, xn2);

    gemm_bf16_k<256, 2, 8, 3><<<2048, 256, 0, stream>>>(xn2, f1T, f1_b, nullptr, hbuf, 1024);
    gemm_bf16_k<1024, 3, 2, 1><<<512, 256, 0, stream>>>(hbuf, f2T, f2_b, x1, out, 256);
}